// Round 6
// baseline (989.022 us; speedup 1.0000x reference)
//
#include <hip/hip_runtime.h>
#include <stdint.h>
#include <stddef.h>

#define B_DIM 2048
#define FIN   4096
#define FOUT  2048
#define NITER 10
#define SMIN  1e-5f

// GEMM1 fp8 pre-scales (exact powers of 2): Wn*2^14 <= ~16 < 448, h*2^8 <= 256 < 448
#define WSCALE 16384.0f
#define HSCALE 256.0f
#define OUTSCALE1 (1.0f / 4194304.0f)   // 2^-22 = 1/(WSCALE*HSCALE)
// GEMM2 i8 scales: ratio*56 <= ~118 < 127; Wn per-row 126/wmax
#define RS_I8 56.0f

typedef float floatx16 __attribute__((ext_vector_type(16)));
typedef int   intx4    __attribute__((ext_vector_type(4)));
typedef int   intx8    __attribute__((ext_vector_type(8)));
typedef int   intx16   __attribute__((ext_vector_type(16)));

__device__ inline unsigned short f2bf(float f) {
    unsigned int u = __float_as_uint(f);
    u += 0x7fffu + ((u >> 16) & 1u);
    return (unsigned short)(u >> 16);
}
__device__ inline float bflo(unsigned int u) { return __uint_as_float(u << 16); }
__device__ inline float bfhi(unsigned int u) { return __uint_as_float(u & 0xffff0000u); }
__device__ inline unsigned int pack2(float a, float b) {
    return (unsigned int)f2bf(a) | ((unsigned int)f2bf(b) << 16);
}

__device__ inline void async16(const void* g, void* l) {
    __builtin_amdgcn_global_load_lds(
        (const __attribute__((address_space(1))) void*)g,
        (__attribute__((address_space(3))) void*)l, 16, 0, 0);
}

__device__ inline float block_row_sum(float v) {
    #pragma unroll
    for (int o = 32; o > 0; o >>= 1) v += __shfl_down(v, o, 64);
    __shared__ float red[4];
    const int lane = threadIdx.x & 63, w = threadIdx.x >> 6;
    if (lane == 0) red[w] = v;
    __syncthreads();
    return red[0] + red[1] + red[2] + red[3];
}

__device__ inline void block_sum_max(float s, float m, float* os, float* om) {
    #pragma unroll
    for (int o = 32; o > 0; o >>= 1) {
        s += __shfl_down(s, o, 64);
        m = fmaxf(m, __shfl_down(m, o, 64));
    }
    __shared__ float rs[4], rm[4];
    const int lane = threadIdx.x & 63, w = threadIdx.x >> 6;
    if (lane == 0) { rs[w] = s; rm[w] = m; }
    __syncthreads();
    *os = (rs[0] + rs[1]) + (rs[2] + rs[3]);
    *om = fmaxf(fmaxf(rm[0], rm[1]), fmaxf(rm[2], rm[3]));
}

// per W-row: s = rowsum(clip), m = rowmax(clip).
//   Wn8  = fp8(clip/s * 2^14)            (GEMM1 B via transpose; aliased w/ rec)
//   WnI8 = i8(clip * 126/m) in [0,126]   (GEMM2 B, per-row uniform quant)
//   dq   = m / (126 * 56 * s)            (GEMM2 per-output-col dequant)
__global__ __launch_bounds__(256) void k_norm_w(const float* __restrict__ W,
                                                unsigned char* __restrict__ Wn8,
                                                unsigned char* __restrict__ WnI8,
                                                float* __restrict__ dq) {
    const int row = blockIdx.x;
    const float4* src = (const float4*)(W + (size_t)row * FIN);
    float4 vals[4];
    float s = 0.f, m = 0.f;
    #pragma unroll
    for (int i = 0; i < 4; ++i) {
        float4 v = src[i * 256 + threadIdx.x];
        v.x = fmaxf(v.x, SMIN); v.y = fmaxf(v.y, SMIN);
        v.z = fmaxf(v.z, SMIN); v.w = fmaxf(v.w, SMIN);
        vals[i] = v;
        s += (v.x + v.y) + (v.z + v.w);
        m = fmaxf(m, fmaxf(fmaxf(v.x, v.y), fmaxf(v.z, v.w)));
    }
    block_sum_max(s, m, &s, &m);
    s = fmaxf(s, 1e-20f);
    const float inv8 = WSCALE / s;
    const float qi = 126.f / m;
    if (threadIdx.x == 0) dq[row] = m / (126.f * RS_I8 * s);
    unsigned int* d8 = (unsigned int*)(Wn8 + (size_t)row * FIN);
    unsigned int* di = (unsigned int*)(WnI8 + (size_t)row * FIN);
    #pragma unroll
    for (int i = 0; i < 4; ++i) {
        float4 v = vals[i];
        unsigned int u = 0;
        u = (unsigned int)__builtin_amdgcn_cvt_pk_fp8_f32(v.x * inv8, v.y * inv8, (int)u, false);
        u = (unsigned int)__builtin_amdgcn_cvt_pk_fp8_f32(v.z * inv8, v.w * inv8, (int)u, true);
        d8[i * 256 + threadIdx.x] = u;
        const int b0 = (int)(v.x * qi + 0.5f);
        const int b1 = (int)(v.y * qi + 0.5f);
        const int b2 = (int)(v.z * qi + 0.5f);
        const int b3 = (int)(v.w * qi + 0.5f);
        di[i * 256 + threadIdx.x] =
            (unsigned int)b0 | ((unsigned int)b1 << 8) |
            ((unsigned int)b2 << 16) | ((unsigned int)b3 << 24);
    }
}

// xn = x / rowsum(x) -> bf16 packed (B x FIN)
__global__ __launch_bounds__(256) void k_norm_x(const float* __restrict__ x,
                                                unsigned int* __restrict__ xnb) {
    const int row = blockIdx.x;
    const float4* src = (const float4*)(x + (size_t)row * FIN);
    float4 vals[4];
    float s = 0.f;
    #pragma unroll
    for (int j = 0; j < 2; ++j) {
        const int idx = j * 256 + threadIdx.x;
        float4 a = src[2 * idx], b = src[2 * idx + 1];
        vals[2 * j] = a; vals[2 * j + 1] = b;
        s += (fabsf(a.x) + fabsf(a.y)) + (fabsf(a.z) + fabsf(a.w));
        s += (fabsf(b.x) + fabsf(b.y)) + (fabsf(b.z) + fabsf(b.w));
    }
    s = block_row_sum(s);
    const float inv = 1.f / fmaxf(s, 1e-20f);
    uint4* dst = (uint4*)(xnb + (size_t)row * (FIN / 2));
    #pragma unroll
    for (int j = 0; j < 2; ++j) {
        float4 a = vals[2 * j], b = vals[2 * j + 1];
        uint4 o;
        o.x = pack2(a.x * inv, a.y * inv);
        o.y = pack2(a.z * inv, a.w * inv);
        o.z = pack2(b.x * inv, b.y * inv);
        o.w = pack2(b.z * inv, b.w * inv);
        dst[j * 256 + threadIdx.x] = o;
    }
}

// WnT8[i][o] = Wn8[o][i]  (pure byte transpose; B operand of GEMM1)
__global__ __launch_bounds__(256) void k_transpose_fp8(const unsigned char* __restrict__ src,
                                                       unsigned char* __restrict__ dst) {
    __shared__ unsigned char tile[32][33];
    const int bi = blockIdx.x * 32, bo = blockIdx.y * 32;
    const int tx = threadIdx.x, ty = threadIdx.y;  // (32,8)
    #pragma unroll
    for (int j = 0; j < 4; ++j)
        tile[ty + j * 8][tx] = src[(size_t)(bo + ty + j * 8) * FIN + bi + tx];
    __syncthreads();
    #pragma unroll
    for (int j = 0; j < 4; ++j)
        dst[(size_t)(bi + ty + j * 8) * FOUT + bo + tx] = tile[tx][ty + j * 8];
}

// h0 = 1/FOUT: fp32 master + fp8(h*2^8) = fp8(0.125) = 0x20 exactly
__global__ __launch_bounds__(256) void k_init_h(float* __restrict__ h,
                                                unsigned int* __restrict__ h8u) {
    const int i = blockIdx.x * blockDim.x + threadIdx.x;
    const float hv = 1.f / (float)FOUT;
    float4 v; v.x = hv; v.y = hv; v.z = hv; v.w = hv;
    ((float4*)h)[i] = v;
    h8u[i] = 0x20202020u;
}

// GEMM1 (MX fp8, R3-validated): rec = (h8 * WnT8^T) * 2^-22 -> bf16.
// NT, no split-K, 128x128 tile, BK=64, 4 waves each 64x64 = 2x2 of
// v_mfma_scale_f32_32x32x64_f8f6f4 (FMT=fp8, scales = e8m0 1.0 all bytes).
// A/B use the identical (row,k-byte) mapping so internal k-permutation cancels.
// XCD supertile: grid (32N,16M) -> 512 blocks; XCD j owns 8Mx8N rectangle.
__global__ __launch_bounds__(256) void k_gemm_fp8(const unsigned char* __restrict__ A,
                                                  const unsigned char* __restrict__ Bm,
                                                  unsigned short* __restrict__ C,
                                                  int N, int K) {
    __shared__ __align__(16) unsigned char As[128 * 64];  // 8 KB
    __shared__ __align__(16) unsigned char Bs[128 * 64];  // 8 KB
    const int tid  = threadIdx.x;
    const int wave = tid >> 6;
    const int lane = tid & 63;

    const int id = blockIdx.y * 32 + blockIdx.x;   // 0..511
    const int j8 = id & 7, s = id >> 3;            // s in [0,64)
    const int bm = ((j8 >> 2) * 8 + (s >> 3)) * 128;   // 16 M-blocks
    const int bn = ((j8 & 3) * 8 + (s & 7)) * 128;     // 32 N-blocks

    const int wr = (wave >> 1) * 64;
    const int wc = (wave & 1) * 64;
    const int l31 = lane & 31;
    const int half = lane >> 5;

    floatx16 acc[2][2] = {};

    const int lr = lane >> 2;
    const int ks = ((lane & 3) ^ ((lane >> 3) & 3)) * 16;  // bytes
    const unsigned char* ga = A  + (size_t)(bm + wave * 32 + lr) * K + ks;
    const unsigned char* gb = Bm + (size_t)(bn + wave * 32 + lr) * K + ks;

    for (int k0 = 0; k0 < K; k0 += 64) {
        __syncthreads();
        #pragma unroll
        for (int j = 0; j < 2; ++j) {
            async16(ga + (size_t)j * 16 * K + k0, &As[wave * 2048 + j * 1024]);
            async16(gb + (size_t)j * 16 * K + k0, &Bs[wave * 2048 + j * 1024]);
        }
        __syncthreads();

        const int sw = (l31 >> 1) & 3;
        const int c0 = (((half << 1) | 0) ^ sw) << 4;
        const int c1 = (((half << 1) | 1) ^ sw) << 4;
        intx8 af[2], bf[2];
        #pragma unroll
        for (int t = 0; t < 2; ++t) {
            const int ra = (wr + t * 32 + l31) * 64;
            const int rb = (wc + t * 32 + l31) * 64;
            intx4 a0 = *(const intx4*)&As[ra + c0];
            intx4 a1 = *(const intx4*)&As[ra + c1];
            intx4 b0 = *(const intx4*)&Bs[rb + c0];
            intx4 b1 = *(const intx4*)&Bs[rb + c1];
            af[t] = (intx8){a0.x, a0.y, a0.z, a0.w, a1.x, a1.y, a1.z, a1.w};
            bf[t] = (intx8){b0.x, b0.y, b0.z, b0.w, b1.x, b1.y, b1.z, b1.w};
        }
        #pragma unroll
        for (int mt = 0; mt < 2; ++mt)
            #pragma unroll
            for (int nt = 0; nt < 2; ++nt)
                acc[mt][nt] = __builtin_amdgcn_mfma_scale_f32_32x32x64_f8f6f4(
                    af[mt], bf[nt], acc[mt][nt],
                    0, 0, 0, 0x7F7F7F7Fu, 0, 0x7F7F7F7Fu);
    }

    const int row0 = 4 * half;
    #pragma unroll
    for (int mt = 0; mt < 2; ++mt) {
        #pragma unroll
        for (int nt = 0; nt < 2; ++nt) {
            #pragma unroll
            for (int reg = 0; reg < 16; ++reg) {
                const int rr = bm + wr + mt * 32 + row0 + (reg & 3) + 8 * (reg >> 2);
                const int cc = bn + wc + nt * 32 + l31;
                C[(size_t)rr * N + cc] = f2bf(acc[mt][nt][reg] * OUTSCALE1);
            }
        }
    }
}

// GEMM2 (i8, R6): upd_z = (ri8 * WnI8^T) * dq[col], fp32 partials.
// R6 change: accumulators SPLIT per kk (acc[kk][mt][nt], 8 independent
// intx16) and all 8 ds_reads hoisted ahead of all 8 MFMAs -- removes the
// 2-long MFMA dependency chain (kk0->kk1 on same acc) that R5's 41 us /
// MfmaUtil 15.8% pointed to (vs structurally-identical MX-fp8 GEMM1 at
// ~21 us / independent MFMAs). i32 merge in epilogue is exact.
// VGPR ~180 is free: occupancy is grid-capped at 2 blocks/CU (8 waves/CU).
__global__ __launch_bounds__(256) void k_gemm_i8(const unsigned char* __restrict__ A,
                                                 const unsigned char* __restrict__ Bm,
                                                 const float* __restrict__ dq,
                                                 float* __restrict__ C,
                                                 int N, int K, int Ksub) {
    __shared__ __align__(16) unsigned char As[128 * 64];  // 8 KB
    __shared__ __align__(16) unsigned char Bs[128 * 64];  // 8 KB
    const int tid  = threadIdx.x;
    const int wave = tid >> 6;
    const int lane = tid & 63;

    const int id = blockIdx.y * 16 + blockIdx.x;   // 0..255 (z*256 = 0 mod 8)
    const int j8 = id & 7, s = id >> 3;            // s in [0,32)
    const int bm = ((j8 >> 1) * 4 + (s >> 3)) * 128;   // 16 M-blocks
    const int bn = ((j8 & 1) * 8 + (s & 7)) * 128;     // 16 N-blocks

    const int kz = blockIdx.z * Ksub;
    const int wr = (wave >> 1) * 64;
    const int wc = (wave & 1) * 64;
    const int l31 = lane & 31;
    const int half = lane >> 5;

    intx16 acc[2][2][2] = {};   // [kk][mt][nt]

    const int lr = lane >> 2;
    const int ks = ((lane & 3) ^ ((lane >> 3) & 3)) * 16;  // bytes
    const unsigned char* ga = A  + (size_t)(bm + wave * 32 + lr) * K + ks;
    const unsigned char* gb = Bm + (size_t)(bn + wave * 32 + lr) * K + ks;

    for (int k0 = kz; k0 < kz + Ksub; k0 += 64) {
        __syncthreads();
        #pragma unroll
        for (int j = 0; j < 2; ++j) {
            async16(ga + (size_t)j * 16 * K + k0, &As[wave * 2048 + j * 1024]);
            async16(gb + (size_t)j * 16 * K + k0, &Bs[wave * 2048 + j * 1024]);
        }
        __syncthreads();

        const int sw = (l31 >> 1) & 3;
        // chunk for MFMA kk, lane-half q: (kk*2+q)^sw, 16 B each
        const int s0 = ((half) ^ sw) << 4;          // kk=0
        const int s1 = ((2 + half) ^ sw) << 4;      // kk=1
        intx4 af[2][2], bf[2][2];                    // [kk][t]
        #pragma unroll
        for (int t = 0; t < 2; ++t) {
            const int ra = (wr + t * 32 + l31) * 64;
            const int rb = (wc + t * 32 + l31) * 64;
            af[0][t] = *(const intx4*)&As[ra + s0];
            af[1][t] = *(const intx4*)&As[ra + s1];
            bf[0][t] = *(const intx4*)&Bs[rb + s0];
            bf[1][t] = *(const intx4*)&Bs[rb + s1];
        }
        #pragma unroll
        for (int kk = 0; kk < 2; ++kk)
            #pragma unroll
            for (int mt = 0; mt < 2; ++mt)
                #pragma unroll
                for (int nt = 0; nt < 2; ++nt)
                    acc[kk][mt][nt] = __builtin_amdgcn_mfma_i32_32x32x32_i8(
                        af[kk][mt], bf[kk][nt], acc[kk][mt][nt], 0, 0, 0);
    }

    float* Cz = C + (size_t)blockIdx.z * B_DIM * N;
    const int row0 = 4 * half;
    const float d0 = dq[bn + wc + l31];        // nt=0 column
    const float d1 = dq[bn + wc + 32 + l31];   // nt=1 column
    #pragma unroll
    for (int mt = 0; mt < 2; ++mt) {
        #pragma unroll
        for (int nt = 0; nt < 2; ++nt) {
            const float d = nt ? d1 : d0;
            #pragma unroll
            for (int reg = 0; reg < 16; ++reg) {
                const int rr = bm + wr + mt * 32 + row0 + (reg & 3) + 8 * (reg >> 2);
                const int cc = bn + wc + nt * 32 + l31;
                Cz[(size_t)rr * N + cc] =
                    (float)(acc[0][mt][nt][reg] + acc[1][mt][nt][reg]) * d;
            }
        }
    }
}

// recon (bf16); s = rowsum(clip); ri8 = i8(min(xn*s*56/clip, 127))
__global__ __launch_bounds__(256) void k_make_ratio(const unsigned short* __restrict__ rec,
                                                    const unsigned int* __restrict__ xnb,
                                                    unsigned char* __restrict__ ri8) {
    const int row = blockIdx.x;
    float v[16];
    float s = 0.f;
    #pragma unroll
    for (int g = 0; g < 2; ++g) {
        const int idx = g * 256 + threadIdx.x;
        uint4 u = ((const uint4*)(rec + (size_t)row * FIN))[idx];
        float* p = v + g * 8;
        p[0] = bflo(u.x); p[1] = bfhi(u.x); p[2] = bflo(u.y); p[3] = bfhi(u.y);
        p[4] = bflo(u.z); p[5] = bfhi(u.z); p[6] = bflo(u.w); p[7] = bfhi(u.w);
        #pragma unroll
        for (int e = 0; e < 8; ++e) { p[e] = fmaxf(p[e], SMIN); s += p[e]; }
    }
    s = block_row_sum(s);
    const float ss = s * RS_I8;
    #pragma unroll
    for (int g = 0; g < 2; ++g) {
        const int idx = g * 256 + threadIdx.x;
        uint4 xu = ((const uint4*)(xnb + (size_t)row * (FIN / 2)))[idx];
        float* p = v + g * 8;
        float r[8];
        r[0] = bflo(xu.x) * ss / p[0]; r[1] = bfhi(xu.x) * ss / p[1];
        r[2] = bflo(xu.y) * ss / p[2]; r[3] = bfhi(xu.y) * ss / p[3];
        r[4] = bflo(xu.z) * ss / p[4]; r[5] = bfhi(xu.z) * ss / p[5];
        r[6] = bflo(xu.w) * ss / p[6]; r[7] = bfhi(xu.w) * ss / p[7];
        unsigned int q[8];
        #pragma unroll
        for (int e = 0; e < 8; ++e)
            q[e] = (unsigned int)(int)(fminf(r[e], 127.0f) + 0.5f);
        uint2 o;
        o.x = q[0] | (q[1] << 8) | (q[2] << 16) | (q[3] << 24);
        o.y = q[4] | (q[5] << 8) | (q[6] << 16) | (q[7] << 24);
        ((uint2*)(ri8 + (size_t)row * FIN))[idx] = o;
    }
}

// upd = sum fp32 partials; t = clip(h*upd); h' = t/rowsum(t); fp32 master + fp8(h*2^8)
__global__ __launch_bounds__(256) void k_update_h(const float* __restrict__ hin,
                                                  const float* __restrict__ upd,
                                                  int nparts,
                                                  float* __restrict__ hout,
                                                  unsigned int* __restrict__ h8u) {
    const int row = blockIdx.x;
    const float4* hp = (const float4*)(hin + (size_t)row * FOUT);
    float4 vals[2];
    float s = 0.f;
    #pragma unroll
    for (int i = 0; i < 2; ++i) {
        const int idx = i * 256 + threadIdx.x;
        float4 hv = hp[idx];
        float4 uv = ((const float4*)(upd + (size_t)row * FOUT))[idx];
        for (int z = 1; z < nparts; ++z) {
            float4 p = ((const float4*)(upd + (size_t)z * B_DIM * FOUT + (size_t)row * FOUT))[idx];
            uv.x += p.x; uv.y += p.y; uv.z += p.z; uv.w += p.w;
        }
        float4 v;
        v.x = fmaxf(hv.x * uv.x, SMIN);
        v.y = fmaxf(hv.y * uv.y, SMIN);
        v.z = fmaxf(hv.z * uv.z, SMIN);
        v.w = fmaxf(hv.w * uv.w, SMIN);
        vals[i] = v;
        s += (v.x + v.y) + (v.z + v.w);
    }
    s = block_row_sum(s);
    const float inv = 1.f / fmaxf(s, 1e-20f);
    float4* op = (float4*)(hout + (size_t)row * FOUT);
    unsigned int* bp = h8u + (size_t)row * (FOUT / 4);
    #pragma unroll
    for (int i = 0; i < 2; ++i) {
        float4 v = vals[i];
        v.x *= inv; v.y *= inv; v.z *= inv; v.w *= inv;
        op[i * 256 + threadIdx.x] = v;
        unsigned int u = 0;
        u = (unsigned int)__builtin_amdgcn_cvt_pk_fp8_f32(v.x * HSCALE, v.y * HSCALE, (int)u, false);
        u = (unsigned int)__builtin_amdgcn_cvt_pk_fp8_f32(v.z * HSCALE, v.w * HSCALE, (int)u, true);
        bp[i * 256 + threadIdx.x] = u;
    }
}

extern "C" void kernel_launch(void* const* d_in, const int* in_sizes, int n_in,
                              void* d_out, int out_size, void* d_ws, size_t ws_size,
                              hipStream_t stream) {
    const float* x = (const float*)d_in[0];
    const float* W = (const float*)d_in[1];
    float* out = (float*)d_out;

    const size_t UPD_PART = (size_t)B_DIM * FOUT * 4;  // fp32, 16.78 MB
    const size_t FIXED    = 81000000;                  // non-partial buffers
    int S2 = 1;
    if (ws_size >= FIXED + 2 * UPD_PART + (1 << 20)) {
        S2 = 2;
    }

    char* ws = (char*)d_ws;
    size_t off = 0;
    auto alloc = [&](size_t bytes) {
        void* p = ws + off;
        off += (bytes + 255) & ~(size_t)255;
        return p;
    };
    unsigned char*  WnT8 = (unsigned char*)alloc((size_t)FIN * FOUT);      // 8.4 MB
    unsigned char*  WnI8 = (unsigned char*)alloc((size_t)FOUT * FIN);      // 8.4 MB
    float*          dq   = (float*)alloc((size_t)FOUT * 4);                // 8 KB
    unsigned int*   h8u  = (unsigned int*)alloc((size_t)B_DIM * FOUT);     // 4.2 MB
    unsigned char*  ri8  = (unsigned char*)alloc((size_t)B_DIM * FIN);     // 8.4 MB
    unsigned int*   xnb  = (unsigned int*)alloc((size_t)B_DIM * FIN * 2);  // 16.8 MB
    float* h             = (float*)alloc((size_t)B_DIM * FOUT * 4);        // 16.8 MB
    unsigned short* rec  = (unsigned short*)alloc((size_t)B_DIM * FIN * 2);// 16.8 MB
    float* upd           = (float*)alloc(UPD_PART * S2);
    // Wn8 (fp8 master for the GEMM1 transpose) aliases rec: only live during
    // setup, before GEMM1 ever writes rec.
    unsigned char* Wn8 = (unsigned char*)rec;
    (void)in_sizes; (void)n_in; (void)out_size;

    k_norm_w<<<FOUT, 256, 0, stream>>>(W, Wn8, WnI8, dq);
    k_transpose_fp8<<<dim3(FIN / 32, FOUT / 32), dim3(32, 8), 0, stream>>>(Wn8, WnT8);
    k_norm_x<<<B_DIM, 256, 0, stream>>>(x, xnb);
    k_init_h<<<(B_DIM * FOUT) / (256 * 4), 256, 0, stream>>>(h, h8u);

    for (int it = 0; it < NITER; ++it) {
        // recon = h @ Wn : MX fp8 NT, A=h8 (K=FOUT), B=WnT8, bf16 out
        k_gemm_fp8<<<dim3(FIN / 128, B_DIM / 128, 1), 256, 0, stream>>>(
            (const unsigned char*)h8u, WnT8, rec, FIN, FOUT);
        k_make_ratio<<<B_DIM, 256, 0, stream>>>(rec, xnb, ri8);
        // upd = r @ Wn^T : i8 NT, split-K=2 in-grid, A=ri8 (K=FIN), B=WnI8
        k_gemm_i8<<<dim3(FOUT / 128, B_DIM / 128, S2), 256, 0, stream>>>(
            ri8, WnI8, dq, upd, FOUT, FIN, FIN / S2);
        k_update_h<<<B_DIM, 256, 0, stream>>>(h, upd, S2, (it == NITER - 1) ? out : h, h8u);
    }
}

// Round 7
// 867.456 us; speedup vs baseline: 1.1401x; 1.1401x over previous
//
#include <hip/hip_runtime.h>
#include <stdint.h>
#include <stddef.h>

#define B_DIM 2048
#define FIN   4096
#define FOUT  2048
#define NITER 10
#define SMIN  1e-5f

// GEMM1 fp8 pre-scales (exact powers of 2): Wn*2^14 <= ~16 < 448, h*2^8 <= 256 < 448
#define WSCALE 16384.0f
#define HSCALE 256.0f
#define OUTSCALE1 (1.0f / 4194304.0f)   // 2^-22 = 1/(WSCALE*HSCALE)
// GEMM2 i8 scales: ratio*56 <= ~118 < 127; Wn per-row 126/wmax
#define RS_I8 56.0f

typedef float floatx16 __attribute__((ext_vector_type(16)));
typedef int   intx4    __attribute__((ext_vector_type(4)));
typedef int   intx8    __attribute__((ext_vector_type(8)));
typedef int   intx16   __attribute__((ext_vector_type(16)));

__device__ inline unsigned short f2bf(float f) {
    unsigned int u = __float_as_uint(f);
    u += 0x7fffu + ((u >> 16) & 1u);
    return (unsigned short)(u >> 16);
}
__device__ inline float bflo(unsigned int u) { return __uint_as_float(u << 16); }
__device__ inline float bfhi(unsigned int u) { return __uint_as_float(u & 0xffff0000u); }
__device__ inline unsigned int pack2(float a, float b) {
    return (unsigned int)f2bf(a) | ((unsigned int)f2bf(b) << 16);
}

__device__ inline void async16(const void* g, void* l) {
    __builtin_amdgcn_global_load_lds(
        (const __attribute__((address_space(1))) void*)g,
        (__attribute__((address_space(3))) void*)l, 16, 0, 0);
}

__device__ inline float block_row_sum(float v) {
    #pragma unroll
    for (int o = 32; o > 0; o >>= 1) v += __shfl_down(v, o, 64);
    __shared__ float red[4];
    const int lane = threadIdx.x & 63, w = threadIdx.x >> 6;
    if (lane == 0) red[w] = v;
    __syncthreads();
    return red[0] + red[1] + red[2] + red[3];
}

__device__ inline void block_sum_max(float s, float m, float* os, float* om) {
    #pragma unroll
    for (int o = 32; o > 0; o >>= 1) {
        s += __shfl_down(s, o, 64);
        m = fmaxf(m, __shfl_down(m, o, 64));
    }
    __shared__ float rs[4], rm[4];
    const int lane = threadIdx.x & 63, w = threadIdx.x >> 6;
    if (lane == 0) { rs[w] = s; rm[w] = m; }
    __syncthreads();
    *os = (rs[0] + rs[1]) + (rs[2] + rs[3]);
    *om = fmaxf(fmaxf(rm[0], rm[1]), fmaxf(rm[2], rm[3]));
}

// per W-row: s = rowsum(clip), m = rowmax(clip).
//   Wn8  = fp8(clip/s * 2^14)            (GEMM1 B via transpose; aliased w/ rec)
//   WnI8 = i8(clip * 126/m) in [0,126]   (GEMM2 B, per-row uniform quant)
//   dq   = m / (126 * 56 * s)            (GEMM2 per-output-col dequant)
__global__ __launch_bounds__(256) void k_norm_w(const float* __restrict__ W,
                                                unsigned char* __restrict__ Wn8,
                                                unsigned char* __restrict__ WnI8,
                                                float* __restrict__ dq) {
    const int row = blockIdx.x;
    const float4* src = (const float4*)(W + (size_t)row * FIN);
    float4 vals[4];
    float s = 0.f, m = 0.f;
    #pragma unroll
    for (int i = 0; i < 4; ++i) {
        float4 v = src[i * 256 + threadIdx.x];
        v.x = fmaxf(v.x, SMIN); v.y = fmaxf(v.y, SMIN);
        v.z = fmaxf(v.z, SMIN); v.w = fmaxf(v.w, SMIN);
        vals[i] = v;
        s += (v.x + v.y) + (v.z + v.w);
        m = fmaxf(m, fmaxf(fmaxf(v.x, v.y), fmaxf(v.z, v.w)));
    }
    block_sum_max(s, m, &s, &m);
    s = fmaxf(s, 1e-20f);
    const float inv8 = WSCALE / s;
    const float qi = 126.f / m;
    if (threadIdx.x == 0) dq[row] = m / (126.f * RS_I8 * s);
    unsigned int* d8 = (unsigned int*)(Wn8 + (size_t)row * FIN);
    unsigned int* di = (unsigned int*)(WnI8 + (size_t)row * FIN);
    #pragma unroll
    for (int i = 0; i < 4; ++i) {
        float4 v = vals[i];
        unsigned int u = 0;
        u = (unsigned int)__builtin_amdgcn_cvt_pk_fp8_f32(v.x * inv8, v.y * inv8, (int)u, false);
        u = (unsigned int)__builtin_amdgcn_cvt_pk_fp8_f32(v.z * inv8, v.w * inv8, (int)u, true);
        d8[i * 256 + threadIdx.x] = u;
        const int b0 = (int)(v.x * qi + 0.5f);
        const int b1 = (int)(v.y * qi + 0.5f);
        const int b2 = (int)(v.z * qi + 0.5f);
        const int b3 = (int)(v.w * qi + 0.5f);
        di[i * 256 + threadIdx.x] =
            (unsigned int)b0 | ((unsigned int)b1 << 8) |
            ((unsigned int)b2 << 16) | ((unsigned int)b3 << 24);
    }
}

// xn = x / rowsum(x) -> bf16 packed (B x FIN)
__global__ __launch_bounds__(256) void k_norm_x(const float* __restrict__ x,
                                                unsigned int* __restrict__ xnb) {
    const int row = blockIdx.x;
    const float4* src = (const float4*)(x + (size_t)row * FIN);
    float4 vals[4];
    float s = 0.f;
    #pragma unroll
    for (int j = 0; j < 2; ++j) {
        const int idx = j * 256 + threadIdx.x;
        float4 a = src[2 * idx], b = src[2 * idx + 1];
        vals[2 * j] = a; vals[2 * j + 1] = b;
        s += (fabsf(a.x) + fabsf(a.y)) + (fabsf(a.z) + fabsf(a.w));
        s += (fabsf(b.x) + fabsf(b.y)) + (fabsf(b.z) + fabsf(b.w));
    }
    s = block_row_sum(s);
    const float inv = 1.f / fmaxf(s, 1e-20f);
    uint4* dst = (uint4*)(xnb + (size_t)row * (FIN / 2));
    #pragma unroll
    for (int j = 0; j < 2; ++j) {
        float4 a = vals[2 * j], b = vals[2 * j + 1];
        uint4 o;
        o.x = pack2(a.x * inv, a.y * inv);
        o.y = pack2(a.z * inv, a.w * inv);
        o.z = pack2(b.x * inv, b.y * inv);
        o.w = pack2(b.z * inv, b.w * inv);
        dst[j * 256 + threadIdx.x] = o;
    }
}

// WnT8[i][o] = Wn8[o][i]  (pure byte transpose; B operand of GEMM1)
__global__ __launch_bounds__(256) void k_transpose_fp8(const unsigned char* __restrict__ src,
                                                       unsigned char* __restrict__ dst) {
    __shared__ unsigned char tile[32][33];
    const int bi = blockIdx.x * 32, bo = blockIdx.y * 32;
    const int tx = threadIdx.x, ty = threadIdx.y;  // (32,8)
    #pragma unroll
    for (int j = 0; j < 4; ++j)
        tile[ty + j * 8][tx] = src[(size_t)(bo + ty + j * 8) * FIN + bi + tx];
    __syncthreads();
    #pragma unroll
    for (int j = 0; j < 4; ++j)
        dst[(size_t)(bi + ty + j * 8) * FOUT + bo + tx] = tile[tx][ty + j * 8];
}

// h0 = 1/FOUT: fp32 master + fp8(h*2^8) = fp8(0.125) = 0x20 exactly
__global__ __launch_bounds__(256) void k_init_h(float* __restrict__ h,
                                                unsigned int* __restrict__ h8u) {
    const int i = blockIdx.x * blockDim.x + threadIdx.x;
    const float hv = 1.f / (float)FOUT;
    float4 v; v.x = hv; v.y = hv; v.z = hv; v.w = hv;
    ((float4*)h)[i] = v;
    h8u[i] = 0x20202020u;
}

// GEMM1 (MX fp8, R7: double-buffered LDS): rec = (h8 * WnT8^T) * 2^-22 -> bf16.
// NT, no split-K, 128x128 tile, BK=64, 4 waves each 64x64 = 2x2 of
// v_mfma_scale_f32_32x32x64_f8f6f4 (FMT=fp8, scales = e8m0 1.0 all bytes).
// T3-minimal 2-phase: prologue-stage tile 0; each iter {barrier (implicit
// vmcnt(0) drain validates tile t), issue stage(t+1) into the other buffer,
// compute tile t}. Load latency overlaps compute; ONE barrier/tile.
// XCD supertile: grid (32N,16M) -> 512 blocks; XCD j owns 8Mx8N rectangle.
__global__ __launch_bounds__(256) void k_gemm_fp8(const unsigned char* __restrict__ A,
                                                  const unsigned char* __restrict__ Bm,
                                                  unsigned short* __restrict__ C,
                                                  int N, int K) {
    __shared__ __align__(16) unsigned char As[2][128 * 64];  // 16 KB
    __shared__ __align__(16) unsigned char Bs[2][128 * 64];  // 16 KB
    const int tid  = threadIdx.x;
    const int wave = tid >> 6;
    const int lane = tid & 63;

    const int id = blockIdx.y * 32 + blockIdx.x;   // 0..511
    const int j8 = id & 7, s = id >> 3;            // s in [0,64)
    const int bm = ((j8 >> 2) * 8 + (s >> 3)) * 128;   // 16 M-blocks
    const int bn = ((j8 & 3) * 8 + (s & 7)) * 128;     // 32 N-blocks

    const int wr = (wave >> 1) * 64;
    const int wc = (wave & 1) * 64;
    const int l31 = lane & 31;
    const int half = lane >> 5;

    floatx16 acc[2][2] = {};

    const int lr = lane >> 2;
    const int ks = ((lane & 3) ^ ((lane >> 3) & 3)) * 16;  // bytes
    const unsigned char* ga = A  + (size_t)(bm + wave * 32 + lr) * K + ks;
    const unsigned char* gb = Bm + (size_t)(bn + wave * 32 + lr) * K + ks;

    auto stage = [&](int k0, int buf) {
        #pragma unroll
        for (int j = 0; j < 2; ++j) {
            async16(ga + (size_t)j * 16 * K + k0, &As[buf][wave * 2048 + j * 1024]);
            async16(gb + (size_t)j * 16 * K + k0, &Bs[buf][wave * 2048 + j * 1024]);
        }
    };

    const int nt = K >> 6;
    stage(0, 0);
    int cur = 0;
    for (int t = 0; t < nt; ++t) {
        __syncthreads();                       // drains own vmcnt -> tile t valid
        if (t + 1 < nt) stage((t + 1) << 6, cur ^ 1);   // prefetch next tile

        const int sw = (l31 >> 1) & 3;
        const int c0 = (((half << 1) | 0) ^ sw) << 4;
        const int c1 = (((half << 1) | 1) ^ sw) << 4;
        intx8 af[2], bf[2];
        #pragma unroll
        for (int tt = 0; tt < 2; ++tt) {
            const int ra = (wr + tt * 32 + l31) * 64;
            const int rb = (wc + tt * 32 + l31) * 64;
            intx4 a0 = *(const intx4*)&As[cur][ra + c0];
            intx4 a1 = *(const intx4*)&As[cur][ra + c1];
            intx4 b0 = *(const intx4*)&Bs[cur][rb + c0];
            intx4 b1 = *(const intx4*)&Bs[cur][rb + c1];
            af[tt] = (intx8){a0.x, a0.y, a0.z, a0.w, a1.x, a1.y, a1.z, a1.w};
            bf[tt] = (intx8){b0.x, b0.y, b0.z, b0.w, b1.x, b1.y, b1.z, b1.w};
        }
        #pragma unroll
        for (int mt = 0; mt < 2; ++mt)
            #pragma unroll
            for (int nt2 = 0; nt2 < 2; ++nt2)
                acc[mt][nt2] = __builtin_amdgcn_mfma_scale_f32_32x32x64_f8f6f4(
                    af[mt], bf[nt2], acc[mt][nt2],
                    0, 0, 0, 0x7F7F7F7Fu, 0, 0x7F7F7F7Fu);
        cur ^= 1;
    }

    const int row0 = 4 * half;
    #pragma unroll
    for (int mt = 0; mt < 2; ++mt) {
        #pragma unroll
        for (int nt2 = 0; nt2 < 2; ++nt2) {
            #pragma unroll
            for (int reg = 0; reg < 16; ++reg) {
                const int rr = bm + wr + mt * 32 + row0 + (reg & 3) + 8 * (reg >> 2);
                const int cc = bn + wc + nt2 * 32 + l31;
                C[(size_t)rr * N + cc] = f2bf(acc[mt][nt2][reg] * OUTSCALE1);
            }
        }
    }
}

// GEMM2 (i8, R7: R5 inner body + double-buffered LDS): upd_z = (ri8 *
// WnI8^T) * dq[col], fp32 partials. v_mfma_i32_32x32x32_i8, i32 accum exact.
// Same T3-minimal 2-phase as GEMM1. Split-K S2=2 in-grid -> 512 blocks
// (2/CU); XCD supertile 4Mx8N per XCD.
__global__ __launch_bounds__(256) void k_gemm_i8(const unsigned char* __restrict__ A,
                                                 const unsigned char* __restrict__ Bm,
                                                 const float* __restrict__ dq,
                                                 float* __restrict__ C,
                                                 int N, int K, int Ksub) {
    __shared__ __align__(16) unsigned char As[2][128 * 64];  // 16 KB
    __shared__ __align__(16) unsigned char Bs[2][128 * 64];  // 16 KB
    const int tid  = threadIdx.x;
    const int wave = tid >> 6;
    const int lane = tid & 63;

    const int id = blockIdx.y * 16 + blockIdx.x;   // 0..255 (z*256 = 0 mod 8)
    const int j8 = id & 7, s = id >> 3;            // s in [0,32)
    const int bm = ((j8 >> 1) * 4 + (s >> 3)) * 128;   // 16 M-blocks
    const int bn = ((j8 & 1) * 8 + (s & 7)) * 128;     // 16 N-blocks

    const int kz = blockIdx.z * Ksub;
    const int wr = (wave >> 1) * 64;
    const int wc = (wave & 1) * 64;
    const int l31 = lane & 31;
    const int half = lane >> 5;

    intx16 acc[2][2] = {};

    const int lr = lane >> 2;
    const int ks = ((lane & 3) ^ ((lane >> 3) & 3)) * 16;  // bytes
    const unsigned char* ga = A  + (size_t)(bm + wave * 32 + lr) * K + ks;
    const unsigned char* gb = Bm + (size_t)(bn + wave * 32 + lr) * K + ks;

    auto stage = [&](int k0, int buf) {
        #pragma unroll
        for (int j = 0; j < 2; ++j) {
            async16(ga + (size_t)j * 16 * K + k0, &As[buf][wave * 2048 + j * 1024]);
            async16(gb + (size_t)j * 16 * K + k0, &Bs[buf][wave * 2048 + j * 1024]);
        }
    };

    const int nt = Ksub >> 6;
    stage(kz, 0);
    int cur = 0;
    for (int t = 0; t < nt; ++t) {
        __syncthreads();                       // drains own vmcnt -> tile t valid
        if (t + 1 < nt) stage(kz + ((t + 1) << 6), cur ^ 1);

        const int sw = (l31 >> 1) & 3;
        #pragma unroll
        for (int kk = 0; kk < 2; ++kk) {
            // MFMA kk covers K bytes [kk*32, kk*32+32); lane-half q holds
            // chunk kk*2+q (16 bytes), stored at slot (kk*2+q)^sw.
            const int slot = (((kk << 1) + half) ^ sw) << 4;
            intx4 af[2], bf[2];
            #pragma unroll
            for (int tt = 0; tt < 2; ++tt) {
                af[tt] = *(const intx4*)&As[cur][(wr + tt * 32 + l31) * 64 + slot];
                bf[tt] = *(const intx4*)&Bs[cur][(wc + tt * 32 + l31) * 64 + slot];
            }
            #pragma unroll
            for (int mt = 0; mt < 2; ++mt)
                #pragma unroll
                for (int nt2 = 0; nt2 < 2; ++nt2)
                    acc[mt][nt2] = __builtin_amdgcn_mfma_i32_32x32x32_i8(
                        af[mt], bf[nt2], acc[mt][nt2], 0, 0, 0);
        }
        cur ^= 1;
    }

    float* Cz = C + (size_t)blockIdx.z * B_DIM * N;
    const int row0 = 4 * half;
    const float d0 = dq[bn + wc + l31];        // nt=0 column
    const float d1 = dq[bn + wc + 32 + l31];   // nt=1 column
    #pragma unroll
    for (int mt = 0; mt < 2; ++mt) {
        #pragma unroll
        for (int nt2 = 0; nt2 < 2; ++nt2) {
            const float d = nt2 ? d1 : d0;
            #pragma unroll
            for (int reg = 0; reg < 16; ++reg) {
                const int rr = bm + wr + mt * 32 + row0 + (reg & 3) + 8 * (reg >> 2);
                const int cc = bn + wc + nt2 * 32 + l31;
                Cz[(size_t)rr * N + cc] = (float)acc[mt][nt2][reg] * d;
            }
        }
    }
}

// recon (bf16); s = rowsum(clip); ri8 = i8(min(xn*s*56/clip, 127))
__global__ __launch_bounds__(256) void k_make_ratio(const unsigned short* __restrict__ rec,
                                                    const unsigned int* __restrict__ xnb,
                                                    unsigned char* __restrict__ ri8) {
    const int row = blockIdx.x;
    float v[16];
    float s = 0.f;
    #pragma unroll
    for (int g = 0; g < 2; ++g) {
        const int idx = g * 256 + threadIdx.x;
        uint4 u = ((const uint4*)(rec + (size_t)row * FIN))[idx];
        float* p = v + g * 8;
        p[0] = bflo(u.x); p[1] = bfhi(u.x); p[2] = bflo(u.y); p[3] = bfhi(u.y);
        p[4] = bflo(u.z); p[5] = bfhi(u.z); p[6] = bflo(u.w); p[7] = bfhi(u.w);
        #pragma unroll
        for (int e = 0; e < 8; ++e) { p[e] = fmaxf(p[e], SMIN); s += p[e]; }
    }
    s = block_row_sum(s);
    const float ss = s * RS_I8;
    #pragma unroll
    for (int g = 0; g < 2; ++g) {
        const int idx = g * 256 + threadIdx.x;
        uint4 xu = ((const uint4*)(xnb + (size_t)row * (FIN / 2)))[idx];
        float* p = v + g * 8;
        float r[8];
        r[0] = bflo(xu.x) * ss / p[0]; r[1] = bfhi(xu.x) * ss / p[1];
        r[2] = bflo(xu.y) * ss / p[2]; r[3] = bfhi(xu.y) * ss / p[3];
        r[4] = bflo(xu.z) * ss / p[4]; r[5] = bfhi(xu.z) * ss / p[5];
        r[6] = bflo(xu.w) * ss / p[6]; r[7] = bfhi(xu.w) * ss / p[7];
        unsigned int q[8];
        #pragma unroll
        for (int e = 0; e < 8; ++e)
            q[e] = (unsigned int)(int)(fminf(r[e], 127.0f) + 0.5f);
        uint2 o;
        o.x = q[0] | (q[1] << 8) | (q[2] << 16) | (q[3] << 24);
        o.y = q[4] | (q[5] << 8) | (q[6] << 16) | (q[7] << 24);
        ((uint2*)(ri8 + (size_t)row * FIN))[idx] = o;
    }
}

// upd = sum fp32 partials; t = clip(h*upd); h' = t/rowsum(t); fp32 master + fp8(h*2^8)
__global__ __launch_bounds__(256) void k_update_h(const float* __restrict__ hin,
                                                  const float* __restrict__ upd,
                                                  int nparts,
                                                  float* __restrict__ hout,
                                                  unsigned int* __restrict__ h8u) {
    const int row = blockIdx.x;
    const float4* hp = (const float4*)(hin + (size_t)row * FOUT);
    float4 vals[2];
    float s = 0.f;
    #pragma unroll
    for (int i = 0; i < 2; ++i) {
        const int idx = i * 256 + threadIdx.x;
        float4 hv = hp[idx];
        float4 uv = ((const float4*)(upd + (size_t)row * FOUT))[idx];
        for (int z = 1; z < nparts; ++z) {
            float4 p = ((const float4*)(upd + (size_t)z * B_DIM * FOUT + (size_t)row * FOUT))[idx];
            uv.x += p.x; uv.y += p.y; uv.z += p.z; uv.w += p.w;
        }
        float4 v;
        v.x = fmaxf(hv.x * uv.x, SMIN);
        v.y = fmaxf(hv.y * uv.y, SMIN);
        v.z = fmaxf(hv.z * uv.z, SMIN);
        v.w = fmaxf(hv.w * uv.w, SMIN);
        vals[i] = v;
        s += (v.x + v.y) + (v.z + v.w);
    }
    s = block_row_sum(s);
    const float inv = 1.f / fmaxf(s, 1e-20f);
    float4* op = (float4*)(hout + (size_t)row * FOUT);
    unsigned int* bp = h8u + (size_t)row * (FOUT / 4);
    #pragma unroll
    for (int i = 0; i < 2; ++i) {
        float4 v = vals[i];
        v.x *= inv; v.y *= inv; v.z *= inv; v.w *= inv;
        op[i * 256 + threadIdx.x] = v;
        unsigned int u = 0;
        u = (unsigned int)__builtin_amdgcn_cvt_pk_fp8_f32(v.x * HSCALE, v.y * HSCALE, (int)u, false);
        u = (unsigned int)__builtin_amdgcn_cvt_pk_fp8_f32(v.z * HSCALE, v.w * HSCALE, (int)u, true);
        bp[i * 256 + threadIdx.x] = u;
    }
}

extern "C" void kernel_launch(void* const* d_in, const int* in_sizes, int n_in,
                              void* d_out, int out_size, void* d_ws, size_t ws_size,
                              hipStream_t stream) {
    const float* x = (const float*)d_in[0];
    const float* W = (const float*)d_in[1];
    float* out = (float*)d_out;

    const size_t UPD_PART = (size_t)B_DIM * FOUT * 4;  // fp32, 16.78 MB
    const size_t FIXED    = 81000000;                  // non-partial buffers
    int S2 = 1;
    if (ws_size >= FIXED + 2 * UPD_PART + (1 << 20)) {
        S2 = 2;
    }

    char* ws = (char*)d_ws;
    size_t off = 0;
    auto alloc = [&](size_t bytes) {
        void* p = ws + off;
        off += (bytes + 255) & ~(size_t)255;
        return p;
    };
    unsigned char*  WnT8 = (unsigned char*)alloc((size_t)FIN * FOUT);      // 8.4 MB
    unsigned char*  WnI8 = (unsigned char*)alloc((size_t)FOUT * FIN);      // 8.4 MB
    float*          dq   = (float*)alloc((size_t)FOUT * 4);                // 8 KB
    unsigned int*   h8u  = (unsigned int*)alloc((size_t)B_DIM * FOUT);     // 4.2 MB
    unsigned char*  ri8  = (unsigned char*)alloc((size_t)B_DIM * FIN);     // 8.4 MB
    unsigned int*   xnb  = (unsigned int*)alloc((size_t)B_DIM * FIN * 2);  // 16.8 MB
    float* h             = (float*)alloc((size_t)B_DIM * FOUT * 4);        // 16.8 MB
    unsigned short* rec  = (unsigned short*)alloc((size_t)B_DIM * FIN * 2);// 16.8 MB
    float* upd           = (float*)alloc(UPD_PART * S2);
    // Wn8 (fp8 master for the GEMM1 transpose) aliases rec: only live during
    // setup, before GEMM1 ever writes rec.
    unsigned char* Wn8 = (unsigned char*)rec;
    (void)in_sizes; (void)n_in; (void)out_size;

    k_norm_w<<<FOUT, 256, 0, stream>>>(W, Wn8, WnI8, dq);
    k_transpose_fp8<<<dim3(FIN / 32, FOUT / 32), dim3(32, 8), 0, stream>>>(Wn8, WnT8);
    k_norm_x<<<B_DIM, 256, 0, stream>>>(x, xnb);
    k_init_h<<<(B_DIM * FOUT) / (256 * 4), 256, 0, stream>>>(h, h8u);

    for (int it = 0; it < NITER; ++it) {
        // recon = h @ Wn : MX fp8 NT dbuf, A=h8 (K=FOUT), B=WnT8, bf16 out
        k_gemm_fp8<<<dim3(FIN / 128, B_DIM / 128, 1), 256, 0, stream>>>(
            (const unsigned char*)h8u, WnT8, rec, FIN, FOUT);
        k_make_ratio<<<B_DIM, 256, 0, stream>>>(rec, xnb, ri8);
        // upd = r @ Wn^T : i8 NT dbuf, split-K=2 in-grid, A=ri8 (K=FIN), B=WnI8
        k_gemm_i8<<<dim3(FOUT / 128, B_DIM / 128, S2), 256, 0, stream>>>(
            ri8, WnI8, dq, upd, FOUT, FIN, FIN / S2);
        k_update_h<<<B_DIM, 256, 0, stream>>>(h, upd, S2, (it == NITER - 1) ? out : h, h8u);
    }
}

// Round 9
// 780.470 us; speedup vs baseline: 1.2672x; 1.1115x over previous
//
#include <hip/hip_runtime.h>
#include <stdint.h>
#include <stddef.h>

#define B_DIM 2048
#define FIN   4096
#define FOUT  2048
#define NITER 10
#define SMIN  1e-5f

// GEMM1 fp8 pre-scales (exact powers of 2): Wn*2^14 <= ~16 < 448, h*2^8 <= 256 < 448
#define WSCALE 16384.0f
#define HSCALE 256.0f
#define OUTSCALE1 (1.0f / 4194304.0f)   // 2^-22 = 1/(WSCALE*HSCALE)
// GEMM2 i8 scales: ratio*56 <= ~118 < 127; Wn per-row 126/wmax
#define RS_I8 56.0f

typedef float floatx16 __attribute__((ext_vector_type(16)));
typedef int   intx4    __attribute__((ext_vector_type(4)));
typedef int   intx8    __attribute__((ext_vector_type(8)));
typedef int   intx16   __attribute__((ext_vector_type(16)));

__device__ inline unsigned short f2bf(float f) {
    unsigned int u = __float_as_uint(f);
    u += 0x7fffu + ((u >> 16) & 1u);
    return (unsigned short)(u >> 16);
}
__device__ inline float bflo(unsigned int u) { return __uint_as_float(u << 16); }
__device__ inline float bfhi(unsigned int u) { return __uint_as_float(u & 0xffff0000u); }
__device__ inline unsigned int pack2(float a, float b) {
    return (unsigned int)f2bf(a) | ((unsigned int)f2bf(b) << 16);
}

__device__ inline void async16(const void* g, void* l) {
    __builtin_amdgcn_global_load_lds(
        (const __attribute__((address_space(1))) void*)g,
        (__attribute__((address_space(3))) void*)l, 16, 0, 0);
}

__device__ inline float block_row_sum(float v) {
    #pragma unroll
    for (int o = 32; o > 0; o >>= 1) v += __shfl_down(v, o, 64);
    __shared__ float red[4];
    const int lane = threadIdx.x & 63, w = threadIdx.x >> 6;
    if (lane == 0) red[w] = v;
    __syncthreads();
    return red[0] + red[1] + red[2] + red[3];
}

__device__ inline void block_sum_max(float s, float m, float* os, float* om) {
    #pragma unroll
    for (int o = 32; o > 0; o >>= 1) {
        s += __shfl_down(s, o, 64);
        m = fmaxf(m, __shfl_down(m, o, 64));
    }
    __shared__ float rs[4], rm[4];
    const int lane = threadIdx.x & 63, w = threadIdx.x >> 6;
    if (lane == 0) { rs[w] = s; rm[w] = m; }
    __syncthreads();
    *os = (rs[0] + rs[1]) + (rs[2] + rs[3]);
    *om = fmaxf(fmaxf(rm[0], rm[1]), fmaxf(rm[2], rm[3]));
}

// per W-row: s = rowsum(clip), m = rowmax(clip).
//   Wn8  = fp8(clip/s * 2^14)            (GEMM1 B via transpose; aliased w/ rec)
//   WnI8 = i8(clip * 126/m) in [0,126]   (GEMM2 B, per-row uniform quant)
//   dq   = m / (126 * 56 * s)            (GEMM2 per-output-col dequant)
__global__ __launch_bounds__(256) void k_norm_w(const float* __restrict__ W,
                                                unsigned char* __restrict__ Wn8,
                                                unsigned char* __restrict__ WnI8,
                                                float* __restrict__ dq) {
    const int row = blockIdx.x;
    const float4* src = (const float4*)(W + (size_t)row * FIN);
    float4 vals[4];
    float s = 0.f, m = 0.f;
    #pragma unroll
    for (int i = 0; i < 4; ++i) {
        float4 v = src[i * 256 + threadIdx.x];
        v.x = fmaxf(v.x, SMIN); v.y = fmaxf(v.y, SMIN);
        v.z = fmaxf(v.z, SMIN); v.w = fmaxf(v.w, SMIN);
        vals[i] = v;
        s += (v.x + v.y) + (v.z + v.w);
        m = fmaxf(m, fmaxf(fmaxf(v.x, v.y), fmaxf(v.z, v.w)));
    }
    block_sum_max(s, m, &s, &m);
    s = fmaxf(s, 1e-20f);
    const float inv8 = WSCALE / s;
    const float qi = 126.f / m;
    if (threadIdx.x == 0) dq[row] = m / (126.f * RS_I8 * s);
    unsigned int* d8 = (unsigned int*)(Wn8 + (size_t)row * FIN);
    unsigned int* di = (unsigned int*)(WnI8 + (size_t)row * FIN);
    #pragma unroll
    for (int i = 0; i < 4; ++i) {
        float4 v = vals[i];
        unsigned int u = 0;
        u = (unsigned int)__builtin_amdgcn_cvt_pk_fp8_f32(v.x * inv8, v.y * inv8, (int)u, false);
        u = (unsigned int)__builtin_amdgcn_cvt_pk_fp8_f32(v.z * inv8, v.w * inv8, (int)u, true);
        d8[i * 256 + threadIdx.x] = u;
        const int b0 = (int)(v.x * qi + 0.5f);
        const int b1 = (int)(v.y * qi + 0.5f);
        const int b2 = (int)(v.z * qi + 0.5f);
        const int b3 = (int)(v.w * qi + 0.5f);
        di[i * 256 + threadIdx.x] =
            (unsigned int)b0 | ((unsigned int)b1 << 8) |
            ((unsigned int)b2 << 16) | ((unsigned int)b3 << 24);
    }
}

// xn = x / rowsum(x) -> bf16 packed (B x FIN)
__global__ __launch_bounds__(256) void k_norm_x(const float* __restrict__ x,
                                                unsigned int* __restrict__ xnb) {
    const int row = blockIdx.x;
    const float4* src = (const float4*)(x + (size_t)row * FIN);
    float4 vals[4];
    float s = 0.f;
    #pragma unroll
    for (int j = 0; j < 2; ++j) {
        const int idx = j * 256 + threadIdx.x;
        float4 a = src[2 * idx], b = src[2 * idx + 1];
        vals[2 * j] = a; vals[2 * j + 1] = b;
        s += (fabsf(a.x) + fabsf(a.y)) + (fabsf(a.z) + fabsf(a.w));
        s += (fabsf(b.x) + fabsf(b.y)) + (fabsf(b.z) + fabsf(b.w));
    }
    s = block_row_sum(s);
    const float inv = 1.f / fmaxf(s, 1e-20f);
    uint4* dst = (uint4*)(xnb + (size_t)row * (FIN / 2));
    #pragma unroll
    for (int j = 0; j < 2; ++j) {
        float4 a = vals[2 * j], b = vals[2 * j + 1];
        uint4 o;
        o.x = pack2(a.x * inv, a.y * inv);
        o.y = pack2(a.z * inv, a.w * inv);
        o.z = pack2(b.x * inv, b.y * inv);
        o.w = pack2(b.z * inv, b.w * inv);
        dst[j * 256 + threadIdx.x] = o;
    }
}

// WnT8[i][o] = Wn8[o][i]  (pure byte transpose; B operand of GEMM1)
__global__ __launch_bounds__(256) void k_transpose_fp8(const unsigned char* __restrict__ src,
                                                       unsigned char* __restrict__ dst) {
    __shared__ unsigned char tile[32][33];
    const int bi = blockIdx.x * 32, bo = blockIdx.y * 32;
    const int tx = threadIdx.x, ty = threadIdx.y;  // (32,8)
    #pragma unroll
    for (int j = 0; j < 4; ++j)
        tile[ty + j * 8][tx] = src[(size_t)(bo + ty + j * 8) * FIN + bi + tx];
    __syncthreads();
    #pragma unroll
    for (int j = 0; j < 4; ++j)
        dst[(size_t)(bi + ty + j * 8) * FOUT + bo + tx] = tile[tx][ty + j * 8];
}

// h0 = 1/FOUT: fp32 master + fp8(h*2^8) = fp8(0.125) = 0x20 exactly
__global__ __launch_bounds__(256) void k_init_h(float* __restrict__ h,
                                                unsigned int* __restrict__ h8u) {
    const int i = blockIdx.x * blockDim.x + threadIdx.x;
    const float hv = 1.f / (float)FOUT;
    float4 v; v.x = hv; v.y = hv; v.z = hv; v.w = hv;
    ((float4*)h)[i] = v;
    h8u[i] = 0x20202020u;
}

// GEMM1 (MX fp8, BK=128): rec = (h8 * WnT8^T) * 2^-22 -> bf16.
// NT, no split-K, 128x128 tile, BK=128 (halves barrier/drain count -- the
// measured per-tile fixed cost dominates), dbuf LDS 64 KB (2 blocks/CU =
// 128 KB <= 160, occupancy unchanged). 4 waves each 64x64 = 2x2, two K=64
// v_mfma_scale_f32_32x32x64_f8f6f4 groups per tile, ascending K (numerics
// bit-identical to R7). Staging: lane -> row lane>>3, slot lane&7, global
// chunk (slot ^ (lane>>3)); reads use chunk c at slot c^(row&7) -- row
// stride 128 B = 32 banks, XOR spreads 32 lanes over 8 slots (4-way, same
// as BK=64). XCD supertile: 512 blocks; XCD j owns 8Mx8N rectangle.
__global__ __launch_bounds__(256) void k_gemm_fp8(const unsigned char* __restrict__ A,
                                                  const unsigned char* __restrict__ Bm,
                                                  unsigned short* __restrict__ C,
                                                  int N, int K) {
    __shared__ __align__(16) unsigned char As[2][128 * 128];  // 32 KB
    __shared__ __align__(16) unsigned char Bs[2][128 * 128];  // 32 KB
    const int tid  = threadIdx.x;
    const int wave = tid >> 6;
    const int lane = tid & 63;

    const int id = blockIdx.y * 32 + blockIdx.x;   // 0..511
    const int j8 = id & 7, s = id >> 3;            // s in [0,64)
    const int bm = ((j8 >> 2) * 8 + (s >> 3)) * 128;   // 16 M-blocks
    const int bn = ((j8 & 3) * 8 + (s & 7)) * 128;     // 32 N-blocks

    const int wr = (wave >> 1) * 64;
    const int wc = (wave & 1) * 64;
    const int l31 = lane & 31;
    const int half = lane >> 5;

    floatx16 acc[2][2] = {};

    // staging: lane covers row lr=lane>>3 (of each 8-row group), slot lane&7
    const int lr = lane >> 3;
    const int ks = ((lane & 7) ^ lr) * 16;  // bytes, pre-swizzled global chunk
    const unsigned char* ga = A  + (size_t)(bm + wave * 32 + lr) * K + ks;
    const unsigned char* gb = Bm + (size_t)(bn + wave * 32 + lr) * K + ks;

    auto stage = [&](int k0, int buf) {
        #pragma unroll
        for (int j = 0; j < 4; ++j) {
            async16(ga + (size_t)j * 8 * K + k0, &As[buf][wave * 4096 + j * 1024]);
            async16(gb + (size_t)j * 8 * K + k0, &Bs[buf][wave * 4096 + j * 1024]);
        }
    };

    const int nt = K >> 7;
    stage(0, 0);
    int cur = 0;
    for (int t = 0; t < nt; ++t) {
        __syncthreads();                       // drains own vmcnt -> tile t valid
        if (t + 1 < nt) stage((t + 1) << 7, cur ^ 1);

        const int sw = l31 & 7;
        #pragma unroll
        for (int m = 0; m < 2; ++m) {          // K=64 group, ascending
            const int c0 = ((4 * m + 2 * half) ^ sw) << 4;
            const int c1 = ((4 * m + 2 * half + 1) ^ sw) << 4;
            intx8 af[2], bf[2];
            #pragma unroll
            for (int tt = 0; tt < 2; ++tt) {
                const int ra = (wr + tt * 32 + l31) * 128;
                const int rb = (wc + tt * 32 + l31) * 128;
                intx4 a0 = *(const intx4*)&As[cur][ra + c0];
                intx4 a1 = *(const intx4*)&As[cur][ra + c1];
                intx4 b0 = *(const intx4*)&Bs[cur][rb + c0];
                intx4 b1 = *(const intx4*)&Bs[cur][rb + c1];
                af[tt] = (intx8){a0.x, a0.y, a0.z, a0.w, a1.x, a1.y, a1.z, a1.w};
                bf[tt] = (intx8){b0.x, b0.y, b0.z, b0.w, b1.x, b1.y, b1.z, b1.w};
            }
            #pragma unroll
            for (int mt = 0; mt < 2; ++mt)
                #pragma unroll
                for (int nt2 = 0; nt2 < 2; ++nt2)
                    acc[mt][nt2] = __builtin_amdgcn_mfma_scale_f32_32x32x64_f8f6f4(
                        af[mt], bf[nt2], acc[mt][nt2],
                        0, 0, 0, 0x7F7F7F7Fu, 0, 0x7F7F7F7Fu);
        }
        cur ^= 1;
    }

    const int row0 = 4 * half;
    #pragma unroll
    for (int mt = 0; mt < 2; ++mt) {
        #pragma unroll
        for (int nt2 = 0; nt2 < 2; ++nt2) {
            #pragma unroll
            for (int reg = 0; reg < 16; ++reg) {
                const int rr = bm + wr + mt * 32 + row0 + (reg & 3) + 8 * (reg >> 2);
                const int cc = bn + wc + nt2 * 32 + l31;
                C[(size_t)rr * N + cc] = f2bf(acc[mt][nt2][reg] * OUTSCALE1);
            }
        }
    }
}

// GEMM2 (i8, BK=128): upd_z = (ri8 * WnI8^T) * dq[col], fp32 partials.
// v_mfma_i32_32x32x32_i8, i32 accum exact; same BK=128 dbuf structure as
// GEMM1. Split-K S2=2 in-grid -> 512 blocks (2/CU); XCD supertile 4Mx8N.
__global__ __launch_bounds__(256) void k_gemm_i8(const unsigned char* __restrict__ A,
                                                 const unsigned char* __restrict__ Bm,
                                                 const float* __restrict__ dq,
                                                 float* __restrict__ C,
                                                 int N, int K, int Ksub) {
    __shared__ __align__(16) unsigned char As[2][128 * 128];  // 32 KB
    __shared__ __align__(16) unsigned char Bs[2][128 * 128];  // 32 KB
    const int tid  = threadIdx.x;
    const int wave = tid >> 6;
    const int lane = tid & 63;

    const int id = blockIdx.y * 16 + blockIdx.x;   // 0..255 (z*256 = 0 mod 8)
    const int j8 = id & 7, s = id >> 3;            // s in [0,32)
    const int bm = ((j8 >> 1) * 4 + (s >> 3)) * 128;   // 16 M-blocks
    const int bn = ((j8 & 1) * 8 + (s & 7)) * 128;     // 16 N-blocks

    const int kz = blockIdx.z * Ksub;
    const int wr = (wave >> 1) * 64;
    const int wc = (wave & 1) * 64;
    const int l31 = lane & 31;
    const int half = lane >> 5;

    intx16 acc[2][2] = {};

    const int lr = lane >> 3;
    const int ks = ((lane & 7) ^ lr) * 16;  // bytes
    const unsigned char* ga = A  + (size_t)(bm + wave * 32 + lr) * K + ks;
    const unsigned char* gb = Bm + (size_t)(bn + wave * 32 + lr) * K + ks;

    auto stage = [&](int k0, int buf) {
        #pragma unroll
        for (int j = 0; j < 4; ++j) {
            async16(ga + (size_t)j * 8 * K + k0, &As[buf][wave * 4096 + j * 1024]);
            async16(gb + (size_t)j * 8 * K + k0, &Bs[buf][wave * 4096 + j * 1024]);
        }
    };

    const int nt = Ksub >> 7;
    stage(kz, 0);
    int cur = 0;
    for (int t = 0; t < nt; ++t) {
        __syncthreads();                       // drains own vmcnt -> tile t valid
        if (t + 1 < nt) stage(kz + ((t + 1) << 7), cur ^ 1);

        const int sw = l31 & 7;
        #pragma unroll
        for (int kk = 0; kk < 4; ++kk) {       // K=32 group, ascending
            const int slot = ((2 * kk + half) ^ sw) << 4;
            intx4 af[2], bf[2];
            #pragma unroll
            for (int tt = 0; tt < 2; ++tt) {
                af[tt] = *(const intx4*)&As[cur][(wr + tt * 32 + l31) * 128 + slot];
                bf[tt] = *(const intx4*)&Bs[cur][(wc + tt * 32 + l31) * 128 + slot];
            }
            #pragma unroll
            for (int mt = 0; mt < 2; ++mt)
                #pragma unroll
                for (int nt2 = 0; nt2 < 2; ++nt2)
                    acc[mt][nt2] = __builtin_amdgcn_mfma_i32_32x32x32_i8(
                        af[mt], bf[nt2], acc[mt][nt2], 0, 0, 0);
        }
        cur ^= 1;
    }

    float* Cz = C + (size_t)blockIdx.z * B_DIM * N;
    const int row0 = 4 * half;
    const float d0 = dq[bn + wc + l31];        // nt=0 column
    const float d1 = dq[bn + wc + 32 + l31];   // nt=1 column
    #pragma unroll
    for (int mt = 0; mt < 2; ++mt) {
        #pragma unroll
        for (int nt2 = 0; nt2 < 2; ++nt2) {
            const float d = nt2 ? d1 : d0;
            #pragma unroll
            for (int reg = 0; reg < 16; ++reg) {
                const int rr = bm + wr + mt * 32 + row0 + (reg & 3) + 8 * (reg >> 2);
                const int cc = bn + wc + nt2 * 32 + l31;
                Cz[(size_t)rr * N + cc] = (float)acc[mt][nt2][reg] * d;
            }
        }
    }
}

// recon (bf16); s = rowsum(clip); ri8 = i8(min(xn*s*56/clip, 127))
__global__ __launch_bounds__(256) void k_make_ratio(const unsigned short* __restrict__ rec,
                                                    const unsigned int* __restrict__ xnb,
                                                    unsigned char* __restrict__ ri8) {
    const int row = blockIdx.x;
    float v[16];
    float s = 0.f;
    #pragma unroll
    for (int g = 0; g < 2; ++g) {
        const int idx = g * 256 + threadIdx.x;
        uint4 u = ((const uint4*)(rec + (size_t)row * FIN))[idx];
        float* p = v + g * 8;
        p[0] = bflo(u.x); p[1] = bfhi(u.x); p[2] = bflo(u.y); p[3] = bfhi(u.y);
        p[4] = bflo(u.z); p[5] = bfhi(u.z); p[6] = bflo(u.w); p[7] = bfhi(u.w);
        #pragma unroll
        for (int e = 0; e < 8; ++e) { p[e] = fmaxf(p[e], SMIN); s += p[e]; }
    }
    s = block_row_sum(s);
    const float ss = s * RS_I8;
    #pragma unroll
    for (int g = 0; g < 2; ++g) {
        const int idx = g * 256 + threadIdx.x;
        uint4 xu = ((const uint4*)(xnb + (size_t)row * (FIN / 2)))[idx];
        float* p = v + g * 8;
        float r[8];
        r[0] = bflo(xu.x) * ss / p[0]; r[1] = bfhi(xu.x) * ss / p[1];
        r[2] = bflo(xu.y) * ss / p[2]; r[3] = bfhi(xu.y) * ss / p[3];
        r[4] = bflo(xu.z) * ss / p[4]; r[5] = bfhi(xu.z) * ss / p[5];
        r[6] = bflo(xu.w) * ss / p[6]; r[7] = bfhi(xu.w) * ss / p[7];
        unsigned int q[8];
        #pragma unroll
        for (int e = 0; e < 8; ++e)
            q[e] = (unsigned int)(int)(fminf(r[e], 127.0f) + 0.5f);
        uint2 o;
        o.x = q[0] | (q[1] << 8) | (q[2] << 16) | (q[3] << 24);
        o.y = q[4] | (q[5] << 8) | (q[6] << 16) | (q[7] << 24);
        ((uint2*)(ri8 + (size_t)row * FIN))[idx] = o;
    }
}

// upd = sum fp32 partials; t = clip(h*upd); h' = t/rowsum(t); fp32 master + fp8(h*2^8)
__global__ __launch_bounds__(256) void k_update_h(const float* __restrict__ hin,
                                                  const float* __restrict__ upd,
                                                  int nparts,
                                                  float* __restrict__ hout,
                                                  unsigned int* __restrict__ h8u) {
    const int row = blockIdx.x;
    const float4* hp = (const float4*)(hin + (size_t)row * FOUT);
    float4 vals[2];
    float s = 0.f;
    #pragma unroll
    for (int i = 0; i < 2; ++i) {
        const int idx = i * 256 + threadIdx.x;
        float4 hv = hp[idx];
        float4 uv = ((const float4*)(upd + (size_t)row * FOUT))[idx];
        for (int z = 1; z < nparts; ++z) {
            float4 p = ((const float4*)(upd + (size_t)z * B_DIM * FOUT + (size_t)row * FOUT))[idx];
            uv.x += p.x; uv.y += p.y; uv.z += p.z; uv.w += p.w;
        }
        float4 v;
        v.x = fmaxf(hv.x * uv.x, SMIN);
        v.y = fmaxf(hv.y * uv.y, SMIN);
        v.z = fmaxf(hv.z * uv.z, SMIN);
        v.w = fmaxf(hv.w * uv.w, SMIN);
        vals[i] = v;
        s += (v.x + v.y) + (v.z + v.w);
    }
    s = block_row_sum(s);
    const float inv = 1.f / fmaxf(s, 1e-20f);
    float4* op = (float4*)(hout + (size_t)row * FOUT);
    unsigned int* bp = h8u + (size_t)row * (FOUT / 4);
    #pragma unroll
    for (int i = 0; i < 2; ++i) {
        float4 v = vals[i];
        v.x *= inv; v.y *= inv; v.z *= inv; v.w *= inv;
        op[i * 256 + threadIdx.x] = v;
        unsigned int u = 0;
        u = (unsigned int)__builtin_amdgcn_cvt_pk_fp8_f32(v.x * HSCALE, v.y * HSCALE, (int)u, false);
        u = (unsigned int)__builtin_amdgcn_cvt_pk_fp8_f32(v.z * HSCALE, v.w * HSCALE, (int)u, true);
        bp[i * 256 + threadIdx.x] = u;
    }
}

extern "C" void kernel_launch(void* const* d_in, const int* in_sizes, int n_in,
                              void* d_out, int out_size, void* d_ws, size_t ws_size,
                              hipStream_t stream) {
    const float* x = (const float*)d_in[0];
    const float* W = (const float*)d_in[1];
    float* out = (float*)d_out;

    const size_t UPD_PART = (size_t)B_DIM * FOUT * 4;  // fp32, 16.78 MB
    const size_t FIXED    = 81000000;                  // non-partial buffers
    int S2 = 1;
    if (ws_size >= FIXED + 2 * UPD_PART + (1 << 20)) {
        S2 = 2;
    }

    char* ws = (char*)d_ws;
    size_t off = 0;
    auto alloc = [&](size_t bytes) {
        void* p = ws + off;
        off += (bytes + 255) & ~(size_t)255;
        return p;
    };
    unsigned char*  WnT8 = (unsigned char*)alloc((size_t)FIN * FOUT);      // 8.4 MB
    unsigned char*  WnI8 = (unsigned char*)alloc((size_t)FOUT * FIN);      // 8.4 MB
    float*          dq   = (float*)alloc((size_t)FOUT * 4);                // 8 KB
    unsigned int*   h8u  = (unsigned int*)alloc((size_t)B_DIM * FOUT);     // 4.2 MB
    unsigned char*  ri8  = (unsigned char*)alloc((size_t)B_DIM * FIN);     // 8.4 MB
    unsigned int*   xnb  = (unsigned int*)alloc((size_t)B_DIM * FIN * 2);  // 16.8 MB
    float* h             = (float*)alloc((size_t)B_DIM * FOUT * 4);        // 16.8 MB
    unsigned short* rec  = (unsigned short*)alloc((size_t)B_DIM * FIN * 2);// 16.8 MB
    float* upd           = (float*)alloc(UPD_PART * S2);
    // Wn8 (fp8 master for the GEMM1 transpose) aliases rec: only live during
    // setup, before GEMM1 ever writes rec.
    unsigned char* Wn8 = (unsigned char*)rec;
    (void)in_sizes; (void)n_in; (void)out_size;

    k_norm_w<<<FOUT, 256, 0, stream>>>(W, Wn8, WnI8, dq);
    k_transpose_fp8<<<dim3(FIN / 32, FOUT / 32), dim3(32, 8), 0, stream>>>(Wn8, WnT8);
    k_norm_x<<<B_DIM, 256, 0, stream>>>(x, xnb);
    k_init_h<<<(B_DIM * FOUT) / (256 * 4), 256, 0, stream>>>(h, h8u);

    for (int it = 0; it < NITER; ++it) {
        // recon = h @ Wn : MX fp8 NT BK=128 dbuf, A=h8 (K=FOUT), B=WnT8, bf16 out
        k_gemm_fp8<<<dim3(FIN / 128, B_DIM / 128, 1), 256, 0, stream>>>(
            (const unsigned char*)h8u, WnT8, rec, FIN, FOUT);
        k_make_ratio<<<B_DIM, 256, 0, stream>>>(rec, xnb, ri8);
        // upd = r @ Wn^T : i8 NT BK=128 dbuf, split-K=2 in-grid, A=ri8, B=WnI8
        k_gemm_i8<<<dim3(FOUT / 128, B_DIM / 128, S2), 256, 0, stream>>>(
            ri8, WnI8, dq, upd, FOUT, FIN, FIN / S2);
        k_update_h<<<B_DIM, 256, 0, stream>>>(h, upd, S2, (it == NITER - 1) ? out : h, h8u);
    }
}

// Round 11
// 739.492 us; speedup vs baseline: 1.3374x; 1.0554x over previous
//
#include <hip/hip_runtime.h>
#include <stdint.h>
#include <stddef.h>

#define B_DIM 2048
#define FIN   4096
#define FOUT  2048
#define NITER 10
#define SMIN  1e-5f

// GEMM1 fp8 pre-scales (exact powers of 2): Wn*2^14 <= ~16 < 448, h*2^8 <= 256 < 448
#define WSCALE 16384.0f
#define HSCALE 256.0f
#define OUTSCALE1 (1.0f / 4194304.0f)   // 2^-22 = 1/(WSCALE*HSCALE)
// GEMM2 i8 scales: ratio*56 <= ~118 < 127; Wn per-row 126/wmax
#define RS_I8 56.0f

typedef float floatx16 __attribute__((ext_vector_type(16)));
typedef int   intx4    __attribute__((ext_vector_type(4)));
typedef int   intx8    __attribute__((ext_vector_type(8)));
typedef int   intx16   __attribute__((ext_vector_type(16)));

__device__ inline unsigned short f2bf(float f) {
    unsigned int u = __float_as_uint(f);
    u += 0x7fffu + ((u >> 16) & 1u);
    return (unsigned short)(u >> 16);
}
__device__ inline float bflo(unsigned int u) { return __uint_as_float(u << 16); }
__device__ inline float bfhi(unsigned int u) { return __uint_as_float(u & 0xffff0000u); }
__device__ inline unsigned int pack2(float a, float b) {
    return (unsigned int)f2bf(a) | ((unsigned int)f2bf(b) << 16);
}
// fp16 partial format (R11): 11-bit mantissa, 8x finer than bf16 (R10 failed
// at 2.29e-5; predicted fp16 added err ~2.4e-6). HW v_cvt RTNE both ways.
__device__ inline unsigned short f2h(float f) {
    union { _Float16 h; unsigned short u; } c;
    c.h = (_Float16)f;
    return c.u;
}
__device__ inline float h2f(unsigned short u) {
    union { _Float16 h; unsigned short u; } c;
    c.u = u;
    return (float)c.h;
}

__device__ inline void async16(const void* g, void* l) {
    __builtin_amdgcn_global_load_lds(
        (const __attribute__((address_space(1))) void*)g,
        (__attribute__((address_space(3))) void*)l, 16, 0, 0);
}

__device__ inline float block_row_sum(float v) {
    #pragma unroll
    for (int o = 32; o > 0; o >>= 1) v += __shfl_down(v, o, 64);
    __shared__ float red[4];
    const int lane = threadIdx.x & 63, w = threadIdx.x >> 6;
    if (lane == 0) red[w] = v;
    __syncthreads();
    return red[0] + red[1] + red[2] + red[3];
}

__device__ inline void block_sum_max(float s, float m, float* os, float* om) {
    #pragma unroll
    for (int o = 32; o > 0; o >>= 1) {
        s += __shfl_down(s, o, 64);
        m = fmaxf(m, __shfl_down(m, o, 64));
    }
    __shared__ float rs[4], rm[4];
    const int lane = threadIdx.x & 63, w = threadIdx.x >> 6;
    if (lane == 0) { rs[w] = s; rm[w] = m; }
    __syncthreads();
    *os = (rs[0] + rs[1]) + (rs[2] + rs[3]);
    *om = fmaxf(fmaxf(rm[0], rm[1]), fmaxf(rm[2], rm[3]));
}

// per W-row: s = rowsum(clip), m = rowmax(clip).
//   Wn8  = fp8(clip/s * 2^14)            (GEMM1 B via transpose; aliased w/ rec)
//   WnI8 = i8(clip * 126/m) in [0,126]   (GEMM2 B, per-row uniform quant)
//   dq   = m / (126 * 56 * s)            (GEMM2 per-output-col dequant)
__global__ __launch_bounds__(256) void k_norm_w(const float* __restrict__ W,
                                                unsigned char* __restrict__ Wn8,
                                                unsigned char* __restrict__ WnI8,
                                                float* __restrict__ dq) {
    const int row = blockIdx.x;
    const float4* src = (const float4*)(W + (size_t)row * FIN);
    float4 vals[4];
    float s = 0.f, m = 0.f;
    #pragma unroll
    for (int i = 0; i < 4; ++i) {
        float4 v = src[i * 256 + threadIdx.x];
        v.x = fmaxf(v.x, SMIN); v.y = fmaxf(v.y, SMIN);
        v.z = fmaxf(v.z, SMIN); v.w = fmaxf(v.w, SMIN);
        vals[i] = v;
        s += (v.x + v.y) + (v.z + v.w);
        m = fmaxf(m, fmaxf(fmaxf(v.x, v.y), fmaxf(v.z, v.w)));
    }
    block_sum_max(s, m, &s, &m);
    s = fmaxf(s, 1e-20f);
    const float inv8 = WSCALE / s;
    const float qi = 126.f / m;
    if (threadIdx.x == 0) dq[row] = m / (126.f * RS_I8 * s);
    unsigned int* d8 = (unsigned int*)(Wn8 + (size_t)row * FIN);
    unsigned int* di = (unsigned int*)(WnI8 + (size_t)row * FIN);
    #pragma unroll
    for (int i = 0; i < 4; ++i) {
        float4 v = vals[i];
        unsigned int u = 0;
        u = (unsigned int)__builtin_amdgcn_cvt_pk_fp8_f32(v.x * inv8, v.y * inv8, (int)u, false);
        u = (unsigned int)__builtin_amdgcn_cvt_pk_fp8_f32(v.z * inv8, v.w * inv8, (int)u, true);
        d8[i * 256 + threadIdx.x] = u;
        const int b0 = (int)(v.x * qi + 0.5f);
        const int b1 = (int)(v.y * qi + 0.5f);
        const int b2 = (int)(v.z * qi + 0.5f);
        const int b3 = (int)(v.w * qi + 0.5f);
        di[i * 256 + threadIdx.x] =
            (unsigned int)b0 | ((unsigned int)b1 << 8) |
            ((unsigned int)b2 << 16) | ((unsigned int)b3 << 24);
    }
}

// xn = x / rowsum(x) -> bf16 packed (B x FIN)
__global__ __launch_bounds__(256) void k_norm_x(const float* __restrict__ x,
                                                unsigned int* __restrict__ xnb) {
    const int row = blockIdx.x;
    const float4* src = (const float4*)(x + (size_t)row * FIN);
    float4 vals[4];
    float s = 0.f;
    #pragma unroll
    for (int j = 0; j < 2; ++j) {
        const int idx = j * 256 + threadIdx.x;
        float4 a = src[2 * idx], b = src[2 * idx + 1];
        vals[2 * j] = a; vals[2 * j + 1] = b;
        s += (fabsf(a.x) + fabsf(a.y)) + (fabsf(a.z) + fabsf(a.w));
        s += (fabsf(b.x) + fabsf(b.y)) + (fabsf(b.z) + fabsf(b.w));
    }
    s = block_row_sum(s);
    const float inv = 1.f / fmaxf(s, 1e-20f);
    uint4* dst = (uint4*)(xnb + (size_t)row * (FIN / 2));
    #pragma unroll
    for (int j = 0; j < 2; ++j) {
        float4 a = vals[2 * j], b = vals[2 * j + 1];
        uint4 o;
        o.x = pack2(a.x * inv, a.y * inv);
        o.y = pack2(a.z * inv, a.w * inv);
        o.z = pack2(b.x * inv, b.y * inv);
        o.w = pack2(b.z * inv, b.w * inv);
        dst[j * 256 + threadIdx.x] = o;
    }
}

// WnT8[i][o] = Wn8[o][i]  (pure byte transpose; B operand of GEMM1)
__global__ __launch_bounds__(256) void k_transpose_fp8(const unsigned char* __restrict__ src,
                                                       unsigned char* __restrict__ dst) {
    __shared__ unsigned char tile[32][33];
    const int bi = blockIdx.x * 32, bo = blockIdx.y * 32;
    const int tx = threadIdx.x, ty = threadIdx.y;  // (32,8)
    #pragma unroll
    for (int j = 0; j < 4; ++j)
        tile[ty + j * 8][tx] = src[(size_t)(bo + ty + j * 8) * FIN + bi + tx];
    __syncthreads();
    #pragma unroll
    for (int j = 0; j < 4; ++j)
        dst[(size_t)(bi + ty + j * 8) * FOUT + bo + tx] = tile[tx][ty + j * 8];
}

// h0 = 1/FOUT: fp32 master + fp8(h*2^8) = fp8(0.125) = 0x20 exactly
__global__ __launch_bounds__(256) void k_init_h(float* __restrict__ h,
                                                unsigned int* __restrict__ h8u) {
    const int i = blockIdx.x * blockDim.x + threadIdx.x;
    const float hv = 1.f / (float)FOUT;
    float4 v; v.x = hv; v.y = hv; v.z = hv; v.w = hv;
    ((float4*)h)[i] = v;
    h8u[i] = 0x20202020u;
}

// GEMM1 (MX fp8, BK=128, R9-validated): rec = (h8 * WnT8^T) * 2^-22 -> bf16.
// NT, no split-K, 128x128 tile, BK=128 dbuf (64 KB LDS, 2 blocks/CU), 4
// waves each 64x64 = 2x2, two K=64 v_mfma_scale_f32_32x32x64_f8f6f4 groups
// per tile, ascending K. XCD supertile: 512 blocks; XCD j owns 8Mx8N rect.
__global__ __launch_bounds__(256) void k_gemm_fp8(const unsigned char* __restrict__ A,
                                                  const unsigned char* __restrict__ Bm,
                                                  unsigned short* __restrict__ C,
                                                  int N, int K) {
    __shared__ __align__(16) unsigned char As[2][128 * 128];  // 32 KB
    __shared__ __align__(16) unsigned char Bs[2][128 * 128];  // 32 KB
    const int tid  = threadIdx.x;
    const int wave = tid >> 6;
    const int lane = tid & 63;

    const int id = blockIdx.y * 32 + blockIdx.x;   // 0..511
    const int j8 = id & 7, s = id >> 3;            // s in [0,64)
    const int bm = ((j8 >> 2) * 8 + (s >> 3)) * 128;   // 16 M-blocks
    const int bn = ((j8 & 3) * 8 + (s & 7)) * 128;     // 32 N-blocks

    const int wr = (wave >> 1) * 64;
    const int wc = (wave & 1) * 64;
    const int l31 = lane & 31;
    const int half = lane >> 5;

    floatx16 acc[2][2] = {};

    // staging: lane covers row lr=lane>>3 (of each 8-row group), slot lane&7
    const int lr = lane >> 3;
    const int ks = ((lane & 7) ^ lr) * 16;  // bytes, pre-swizzled global chunk
    const unsigned char* ga = A  + (size_t)(bm + wave * 32 + lr) * K + ks;
    const unsigned char* gb = Bm + (size_t)(bn + wave * 32 + lr) * K + ks;

    auto stage = [&](int k0, int buf) {
        #pragma unroll
        for (int j = 0; j < 4; ++j) {
            async16(ga + (size_t)j * 8 * K + k0, &As[buf][wave * 4096 + j * 1024]);
            async16(gb + (size_t)j * 8 * K + k0, &Bs[buf][wave * 4096 + j * 1024]);
        }
    };

    const int nt = K >> 7;
    stage(0, 0);
    int cur = 0;
    for (int t = 0; t < nt; ++t) {
        __syncthreads();                       // drains own vmcnt -> tile t valid
        if (t + 1 < nt) stage((t + 1) << 7, cur ^ 1);

        const int sw = l31 & 7;
        #pragma unroll
        for (int m = 0; m < 2; ++m) {          // K=64 group, ascending
            const int c0 = ((4 * m + 2 * half) ^ sw) << 4;
            const int c1 = ((4 * m + 2 * half + 1) ^ sw) << 4;
            intx8 af[2], bf[2];
            #pragma unroll
            for (int tt = 0; tt < 2; ++tt) {
                const int ra = (wr + tt * 32 + l31) * 128;
                const int rb = (wc + tt * 32 + l31) * 128;
                intx4 a0 = *(const intx4*)&As[cur][ra + c0];
                intx4 a1 = *(const intx4*)&As[cur][ra + c1];
                intx4 b0 = *(const intx4*)&Bs[cur][rb + c0];
                intx4 b1 = *(const intx4*)&Bs[cur][rb + c1];
                af[tt] = (intx8){a0.x, a0.y, a0.z, a0.w, a1.x, a1.y, a1.z, a1.w};
                bf[tt] = (intx8){b0.x, b0.y, b0.z, b0.w, b1.x, b1.y, b1.z, b1.w};
            }
            #pragma unroll
            for (int mt = 0; mt < 2; ++mt)
                #pragma unroll
                for (int nt2 = 0; nt2 < 2; ++nt2)
                    acc[mt][nt2] = __builtin_amdgcn_mfma_scale_f32_32x32x64_f8f6f4(
                        af[mt], bf[nt2], acc[mt][nt2],
                        0, 0, 0, 0x7F7F7F7Fu, 0, 0x7F7F7F7Fu);
        }
        cur ^= 1;
    }

    const int row0 = 4 * half;
    #pragma unroll
    for (int mt = 0; mt < 2; ++mt) {
        #pragma unroll
        for (int nt2 = 0; nt2 < 2; ++nt2) {
            #pragma unroll
            for (int reg = 0; reg < 16; ++reg) {
                const int rr = bm + wr + mt * 32 + row0 + (reg & 3) + 8 * (reg >> 2);
                const int cc = bn + wc + nt2 * 32 + l31;
                C[(size_t)rr * N + cc] = f2bf(acc[mt][nt2][reg] * OUTSCALE1);
            }
        }
    }
}

// GEMM2 (i8, BK=128; R11: fp16 partials): upd_z = fp16((ri8 * WnI8^T) *
// dq[col]). v_mfma_i32_32x32x32_i8, i32 accum exact; dequant then RTNE to
// fp16 in the epilogue. fp16 keeps R10's traffic halving but with 11-bit
// mantissa (8x finer than bf16, whose 2.29e-5 failed; predicted added err
// ~2.4e-6). Partials ~0.5, well inside fp16 range. Split-K S2=2 in-grid ->
// 512 blocks (2/CU); XCD supertile 4Mx8N per XCD.
__global__ __launch_bounds__(256) void k_gemm_i8(const unsigned char* __restrict__ A,
                                                 const unsigned char* __restrict__ Bm,
                                                 const float* __restrict__ dq,
                                                 unsigned short* __restrict__ C,
                                                 int N, int K, int Ksub) {
    __shared__ __align__(16) unsigned char As[2][128 * 128];  // 32 KB
    __shared__ __align__(16) unsigned char Bs[2][128 * 128];  // 32 KB
    const int tid  = threadIdx.x;
    const int wave = tid >> 6;
    const int lane = tid & 63;

    const int id = blockIdx.y * 16 + blockIdx.x;   // 0..255 (z*256 = 0 mod 8)
    const int j8 = id & 7, s = id >> 3;            // s in [0,32)
    const int bm = ((j8 >> 1) * 4 + (s >> 3)) * 128;   // 16 M-blocks
    const int bn = ((j8 & 1) * 8 + (s & 7)) * 128;     // 16 N-blocks

    const int kz = blockIdx.z * Ksub;
    const int wr = (wave >> 1) * 64;
    const int wc = (wave & 1) * 64;
    const int l31 = lane & 31;
    const int half = lane >> 5;

    intx16 acc[2][2] = {};

    const int lr = lane >> 3;
    const int ks = ((lane & 7) ^ lr) * 16;  // bytes
    const unsigned char* ga = A  + (size_t)(bm + wave * 32 + lr) * K + ks;
    const unsigned char* gb = Bm + (size_t)(bn + wave * 32 + lr) * K + ks;

    auto stage = [&](int k0, int buf) {
        #pragma unroll
        for (int j = 0; j < 4; ++j) {
            async16(ga + (size_t)j * 8 * K + k0, &As[buf][wave * 4096 + j * 1024]);
            async16(gb + (size_t)j * 8 * K + k0, &Bs[buf][wave * 4096 + j * 1024]);
        }
    };

    const int nt = Ksub >> 7;
    stage(kz, 0);
    int cur = 0;
    for (int t = 0; t < nt; ++t) {
        __syncthreads();                       // drains own vmcnt -> tile t valid
        if (t + 1 < nt) stage(kz + ((t + 1) << 7), cur ^ 1);

        const int sw = l31 & 7;
        #pragma unroll
        for (int kk = 0; kk < 4; ++kk) {       // K=32 group, ascending
            const int slot = ((2 * kk + half) ^ sw) << 4;
            intx4 af[2], bf[2];
            #pragma unroll
            for (int tt = 0; tt < 2; ++tt) {
                af[tt] = *(const intx4*)&As[cur][(wr + tt * 32 + l31) * 128 + slot];
                bf[tt] = *(const intx4*)&Bs[cur][(wc + tt * 32 + l31) * 128 + slot];
            }
            #pragma unroll
            for (int mt = 0; mt < 2; ++mt)
                #pragma unroll
                for (int nt2 = 0; nt2 < 2; ++nt2)
                    acc[mt][nt2] = __builtin_amdgcn_mfma_i32_32x32x32_i8(
                        af[mt], bf[nt2], acc[mt][nt2], 0, 0, 0);
        }
        cur ^= 1;
    }

    unsigned short* Cz = C + (size_t)blockIdx.z * B_DIM * N;
    const int row0 = 4 * half;
    const float d0 = dq[bn + wc + l31];        // nt=0 column
    const float d1 = dq[bn + wc + 32 + l31];   // nt=1 column
    #pragma unroll
    for (int mt = 0; mt < 2; ++mt) {
        #pragma unroll
        for (int nt2 = 0; nt2 < 2; ++nt2) {
            const float d = nt2 ? d1 : d0;
            #pragma unroll
            for (int reg = 0; reg < 16; ++reg) {
                const int rr = bm + wr + mt * 32 + row0 + (reg & 3) + 8 * (reg >> 2);
                const int cc = bn + wc + nt2 * 32 + l31;
                Cz[(size_t)rr * N + cc] = f2h((float)acc[mt][nt2][reg] * d);
            }
        }
    }
}

// recon (bf16); s = rowsum(clip); ri8 = i8(min(xn*s*56/clip, 127))
__global__ __launch_bounds__(256) void k_make_ratio(const unsigned short* __restrict__ rec,
                                                    const unsigned int* __restrict__ xnb,
                                                    unsigned char* __restrict__ ri8) {
    const int row = blockIdx.x;
    float v[16];
    float s = 0.f;
    #pragma unroll
    for (int g = 0; g < 2; ++g) {
        const int idx = g * 256 + threadIdx.x;
        uint4 u = ((const uint4*)(rec + (size_t)row * FIN))[idx];
        float* p = v + g * 8;
        p[0] = bflo(u.x); p[1] = bfhi(u.x); p[2] = bflo(u.y); p[3] = bfhi(u.y);
        p[4] = bflo(u.z); p[5] = bfhi(u.z); p[6] = bflo(u.w); p[7] = bfhi(u.w);
        #pragma unroll
        for (int e = 0; e < 8; ++e) { p[e] = fmaxf(p[e], SMIN); s += p[e]; }
    }
    s = block_row_sum(s);
    const float ss = s * RS_I8;
    #pragma unroll
    for (int g = 0; g < 2; ++g) {
        const int idx = g * 256 + threadIdx.x;
        uint4 xu = ((const uint4*)(xnb + (size_t)row * (FIN / 2)))[idx];
        float* p = v + g * 8;
        float r[8];
        r[0] = bflo(xu.x) * ss / p[0]; r[1] = bfhi(xu.x) * ss / p[1];
        r[2] = bflo(xu.y) * ss / p[2]; r[3] = bfhi(xu.y) * ss / p[3];
        r[4] = bflo(xu.z) * ss / p[4]; r[5] = bfhi(xu.z) * ss / p[5];
        r[6] = bflo(xu.w) * ss / p[6]; r[7] = bfhi(xu.w) * ss / p[7];
        unsigned int q[8];
        #pragma unroll
        for (int e = 0; e < 8; ++e)
            q[e] = (unsigned int)(int)(fminf(r[e], 127.0f) + 0.5f);
        uint2 o;
        o.x = q[0] | (q[1] << 8) | (q[2] << 16) | (q[3] << 24);
        o.y = q[4] | (q[5] << 8) | (q[6] << 16) | (q[7] << 24);
        ((uint2*)(ri8 + (size_t)row * FIN))[idx] = o;
    }
}

// upd = sum fp16 partials; t = clip(h*upd); h' = t/rowsum(t); fp32 master + fp8(h*2^8)
__global__ __launch_bounds__(256) void k_update_h(const float* __restrict__ hin,
                                                  const unsigned short* __restrict__ upd,
                                                  int nparts,
                                                  float* __restrict__ hout,
                                                  unsigned int* __restrict__ h8u) {
    const int row = blockIdx.x;
    const float4* hp = (const float4*)(hin + (size_t)row * FOUT);
    float4 vals[2];
    float s = 0.f;
    #pragma unroll
    for (int i = 0; i < 2; ++i) {
        const int idx = i * 256 + threadIdx.x;
        float4 hv = hp[idx];
        uint2 u = ((const uint2*)(upd + (size_t)row * FOUT))[idx];
        float4 uv;
        uv.x = h2f((unsigned short)(u.x & 0xffffu));
        uv.y = h2f((unsigned short)(u.x >> 16));
        uv.z = h2f((unsigned short)(u.y & 0xffffu));
        uv.w = h2f((unsigned short)(u.y >> 16));
        for (int z = 1; z < nparts; ++z) {
            uint2 q = ((const uint2*)(upd + (size_t)z * B_DIM * FOUT + (size_t)row * FOUT))[idx];
            uv.x += h2f((unsigned short)(q.x & 0xffffu));
            uv.y += h2f((unsigned short)(q.x >> 16));
            uv.z += h2f((unsigned short)(q.y & 0xffffu));
            uv.w += h2f((unsigned short)(q.y >> 16));
        }
        float4 v;
        v.x = fmaxf(hv.x * uv.x, SMIN);
        v.y = fmaxf(hv.y * uv.y, SMIN);
        v.z = fmaxf(hv.z * uv.z, SMIN);
        v.w = fmaxf(hv.w * uv.w, SMIN);
        vals[i] = v;
        s += (v.x + v.y) + (v.z + v.w);
    }
    s = block_row_sum(s);
    const float inv = 1.f / fmaxf(s, 1e-20f);
    float4* op = (float4*)(hout + (size_t)row * FOUT);
    unsigned int* bp = h8u + (size_t)row * (FOUT / 4);
    #pragma unroll
    for (int i = 0; i < 2; ++i) {
        float4 v = vals[i];
        v.x *= inv; v.y *= inv; v.z *= inv; v.w *= inv;
        op[i * 256 + threadIdx.x] = v;
        unsigned int u = 0;
        u = (unsigned int)__builtin_amdgcn_cvt_pk_fp8_f32(v.x * HSCALE, v.y * HSCALE, (int)u, false);
        u = (unsigned int)__builtin_amdgcn_cvt_pk_fp8_f32(v.z * HSCALE, v.w * HSCALE, (int)u, true);
        bp[i * 256 + threadIdx.x] = u;
    }
}

extern "C" void kernel_launch(void* const* d_in, const int* in_sizes, int n_in,
                              void* d_out, int out_size, void* d_ws, size_t ws_size,
                              hipStream_t stream) {
    const float* x = (const float*)d_in[0];
    const float* W = (const float*)d_in[1];
    float* out = (float*)d_out;

    const size_t UPD_PART = (size_t)B_DIM * FOUT * 2;  // fp16, 8.4 MB
    const size_t FIXED    = 81000000;                  // non-partial buffers
    int S2 = 1;
    if (ws_size >= FIXED + 2 * UPD_PART + (1 << 20)) {
        S2 = 2;
    }

    char* ws = (char*)d_ws;
    size_t off = 0;
    auto alloc = [&](size_t bytes) {
        void* p = ws + off;
        off += (bytes + 255) & ~(size_t)255;
        return p;
    };
    unsigned char*  WnT8 = (unsigned char*)alloc((size_t)FIN * FOUT);      // 8.4 MB
    unsigned char*  WnI8 = (unsigned char*)alloc((size_t)FOUT * FIN);      // 8.4 MB
    float*          dq   = (float*)alloc((size_t)FOUT * 4);                // 8 KB
    unsigned int*   h8u  = (unsigned int*)alloc((size_t)B_DIM * FOUT);     // 4.2 MB
    unsigned char*  ri8  = (unsigned char*)alloc((size_t)B_DIM * FIN);     // 8.4 MB
    unsigned int*   xnb  = (unsigned int*)alloc((size_t)B_DIM * FIN * 2);  // 16.8 MB
    float* h             = (float*)alloc((size_t)B_DIM * FOUT * 4);        // 16.8 MB
    unsigned short* rec  = (unsigned short*)alloc((size_t)B_DIM * FIN * 2);// 16.8 MB
    unsigned short* upd  = (unsigned short*)alloc(UPD_PART * S2);
    // Wn8 (fp8 master for the GEMM1 transpose) aliases rec: only live during
    // setup, before GEMM1 ever writes rec.
    unsigned char* Wn8 = (unsigned char*)rec;
    (void)in_sizes; (void)n_in; (void)out_size;

    k_norm_w<<<FOUT, 256, 0, stream>>>(W, Wn8, WnI8, dq);
    k_transpose_fp8<<<dim3(FIN / 32, FOUT / 32), dim3(32, 8), 0, stream>>>(Wn8, WnT8);
    k_norm_x<<<B_DIM, 256, 0, stream>>>(x, xnb);
    k_init_h<<<(B_DIM * FOUT) / (256 * 4), 256, 0, stream>>>(h, h8u);

    for (int it = 0; it < NITER; ++it) {
        // recon = h @ Wn : MX fp8 NT BK=128 dbuf, A=h8 (K=FOUT), B=WnT8, bf16 out
        k_gemm_fp8<<<dim3(FIN / 128, B_DIM / 128, 1), 256, 0, stream>>>(
            (const unsigned char*)h8u, WnT8, rec, FIN, FOUT);
        k_make_ratio<<<B_DIM, 256, 0, stream>>>(rec, xnb, ri8);
        // upd = r @ Wn^T : i8 NT BK=128 dbuf, split-K=2 in-grid, fp16 partials
        k_gemm_i8<<<dim3(FOUT / 128, B_DIM / 128, S2), 256, 0, stream>>>(
            ri8, WnI8, dq, upd, FOUT, FIN, FIN / S2);
        k_update_h<<<B_DIM, 256, 0, stream>>>(h, upd, S2, (it == NITER - 1) ? out : h, h8u);
    }
}

// Round 12
// 721.045 us; speedup vs baseline: 1.3716x; 1.0256x over previous
//
#include <hip/hip_runtime.h>
#include <stdint.h>
#include <stddef.h>

#define B_DIM 2048
#define FIN   4096
#define FOUT  2048
#define NITER 10
#define SMIN  1e-5f

// GEMM1 fp8 pre-scales (exact powers of 2): Wn*2^14 <= ~16 < 448, h*2^8 <= 256 < 448
#define WSCALE 16384.0f
#define HSCALE 256.0f
#define OUTSCALE1 (1.0f / 4194304.0f)   // 2^-22 = 1/(WSCALE*HSCALE)
// GEMM2 i8 scales: ratio*56 <= ~118 < 127; Wn per-row 126/wmax
#define RS_I8 56.0f

typedef float floatx16 __attribute__((ext_vector_type(16)));
typedef int   intx4    __attribute__((ext_vector_type(4)));
typedef int   intx8    __attribute__((ext_vector_type(8)));
typedef int   intx16   __attribute__((ext_vector_type(16)));

__device__ inline unsigned short f2bf(float f) {
    unsigned int u = __float_as_uint(f);
    u += 0x7fffu + ((u >> 16) & 1u);
    return (unsigned short)(u >> 16);
}
__device__ inline float bflo(unsigned int u) { return __uint_as_float(u << 16); }
__device__ inline float bfhi(unsigned int u) { return __uint_as_float(u & 0xffff0000u); }
__device__ inline unsigned int pack2(float a, float b) {
    return (unsigned int)f2bf(a) | ((unsigned int)f2bf(b) << 16);
}
// fp16 (R11-validated for partials; R12: also h master). 11-bit mantissa,
// HW v_cvt RTNE both ways. h in [1e-5, ~1.6e-3] is in fp16 normal range;
// 1/2048 = 2^-11 is exact.
__device__ inline unsigned short f2h(float f) {
    union { _Float16 h; unsigned short u; } c;
    c.h = (_Float16)f;
    return c.u;
}
__device__ inline float h2f(unsigned short u) {
    union { _Float16 h; unsigned short u; } c;
    c.u = u;
    return (float)c.h;
}

__device__ inline void async16(const void* g, void* l) {
    __builtin_amdgcn_global_load_lds(
        (const __attribute__((address_space(1))) void*)g,
        (__attribute__((address_space(3))) void*)l, 16, 0, 0);
}

__device__ inline float block_row_sum(float v) {
    #pragma unroll
    for (int o = 32; o > 0; o >>= 1) v += __shfl_down(v, o, 64);
    __shared__ float red[4];
    const int lane = threadIdx.x & 63, w = threadIdx.x >> 6;
    if (lane == 0) red[w] = v;
    __syncthreads();
    return red[0] + red[1] + red[2] + red[3];
}

__device__ inline void block_sum_max(float s, float m, float* os, float* om) {
    #pragma unroll
    for (int o = 32; o > 0; o >>= 1) {
        s += __shfl_down(s, o, 64);
        m = fmaxf(m, __shfl_down(m, o, 64));
    }
    __shared__ float rs[4], rm[4];
    const int lane = threadIdx.x & 63, w = threadIdx.x >> 6;
    if (lane == 0) { rs[w] = s; rm[w] = m; }
    __syncthreads();
    *os = (rs[0] + rs[1]) + (rs[2] + rs[3]);
    *om = fmaxf(fmaxf(rm[0], rm[1]), fmaxf(rm[2], rm[3]));
}

// per W-row: s = rowsum(clip), m = rowmax(clip).
//   Wn8  = fp8(clip/s * 2^14)            (GEMM1 B via transpose; aliased w/ rec)
//   WnI8 = i8(clip * 126/m) in [0,126]   (GEMM2 B, per-row uniform quant)
//   dq   = m / (126 * 56 * s)            (GEMM2 per-output-col dequant)
__global__ __launch_bounds__(256) void k_norm_w(const float* __restrict__ W,
                                                unsigned char* __restrict__ Wn8,
                                                unsigned char* __restrict__ WnI8,
                                                float* __restrict__ dq) {
    const int row = blockIdx.x;
    const float4* src = (const float4*)(W + (size_t)row * FIN);
    float4 vals[4];
    float s = 0.f, m = 0.f;
    #pragma unroll
    for (int i = 0; i < 4; ++i) {
        float4 v = src[i * 256 + threadIdx.x];
        v.x = fmaxf(v.x, SMIN); v.y = fmaxf(v.y, SMIN);
        v.z = fmaxf(v.z, SMIN); v.w = fmaxf(v.w, SMIN);
        vals[i] = v;
        s += (v.x + v.y) + (v.z + v.w);
        m = fmaxf(m, fmaxf(fmaxf(v.x, v.y), fmaxf(v.z, v.w)));
    }
    block_sum_max(s, m, &s, &m);
    s = fmaxf(s, 1e-20f);
    const float inv8 = WSCALE / s;
    const float qi = 126.f / m;
    if (threadIdx.x == 0) dq[row] = m / (126.f * RS_I8 * s);
    unsigned int* d8 = (unsigned int*)(Wn8 + (size_t)row * FIN);
    unsigned int* di = (unsigned int*)(WnI8 + (size_t)row * FIN);
    #pragma unroll
    for (int i = 0; i < 4; ++i) {
        float4 v = vals[i];
        unsigned int u = 0;
        u = (unsigned int)__builtin_amdgcn_cvt_pk_fp8_f32(v.x * inv8, v.y * inv8, (int)u, false);
        u = (unsigned int)__builtin_amdgcn_cvt_pk_fp8_f32(v.z * inv8, v.w * inv8, (int)u, true);
        d8[i * 256 + threadIdx.x] = u;
        const int b0 = (int)(v.x * qi + 0.5f);
        const int b1 = (int)(v.y * qi + 0.5f);
        const int b2 = (int)(v.z * qi + 0.5f);
        const int b3 = (int)(v.w * qi + 0.5f);
        di[i * 256 + threadIdx.x] =
            (unsigned int)b0 | ((unsigned int)b1 << 8) |
            ((unsigned int)b2 << 16) | ((unsigned int)b3 << 24);
    }
}

// xn = x / rowsum(x) -> bf16 packed (B x FIN)
__global__ __launch_bounds__(256) void k_norm_x(const float* __restrict__ x,
                                                unsigned int* __restrict__ xnb) {
    const int row = blockIdx.x;
    const float4* src = (const float4*)(x + (size_t)row * FIN);
    float4 vals[4];
    float s = 0.f;
    #pragma unroll
    for (int j = 0; j < 2; ++j) {
        const int idx = j * 256 + threadIdx.x;
        float4 a = src[2 * idx], b = src[2 * idx + 1];
        vals[2 * j] = a; vals[2 * j + 1] = b;
        s += (fabsf(a.x) + fabsf(a.y)) + (fabsf(a.z) + fabsf(a.w));
        s += (fabsf(b.x) + fabsf(b.y)) + (fabsf(b.z) + fabsf(b.w));
    }
    s = block_row_sum(s);
    const float inv = 1.f / fmaxf(s, 1e-20f);
    uint4* dst = (uint4*)(xnb + (size_t)row * (FIN / 2));
    #pragma unroll
    for (int j = 0; j < 2; ++j) {
        float4 a = vals[2 * j], b = vals[2 * j + 1];
        uint4 o;
        o.x = pack2(a.x * inv, a.y * inv);
        o.y = pack2(a.z * inv, a.w * inv);
        o.z = pack2(b.x * inv, b.y * inv);
        o.w = pack2(b.z * inv, b.w * inv);
        dst[j * 256 + threadIdx.x] = o;
    }
}

// WnT8[i][o] = Wn8[o][i]  (pure byte transpose; B operand of GEMM1)
__global__ __launch_bounds__(256) void k_transpose_fp8(const unsigned char* __restrict__ src,
                                                       unsigned char* __restrict__ dst) {
    __shared__ unsigned char tile[32][33];
    const int bi = blockIdx.x * 32, bo = blockIdx.y * 32;
    const int tx = threadIdx.x, ty = threadIdx.y;  // (32,8)
    #pragma unroll
    for (int j = 0; j < 4; ++j)
        tile[ty + j * 8][tx] = src[(size_t)(bo + ty + j * 8) * FIN + bi + tx];
    __syncthreads();
    #pragma unroll
    for (int j = 0; j < 4; ++j)
        dst[(size_t)(bi + ty + j * 8) * FOUT + bo + tx] = tile[tx][ty + j * 8];
}

// h0 = 1/FOUT = 2^-11: fp16 master 0x1000 exactly + fp8(h*2^8) = 0x20 exactly
__global__ __launch_bounds__(256) void k_init_h(unsigned int* __restrict__ h16,
                                                unsigned int* __restrict__ h8u) {
    const int i = blockIdx.x * blockDim.x + threadIdx.x;
    uint2 v; v.x = 0x10001000u; v.y = 0x10001000u;   // 4x fp16(2^-11)
    ((uint2*)h16)[i] = v;
    h8u[i] = 0x20202020u;
}

// GEMM1 (MX fp8, BK=128, R9-validated): rec = (h8 * WnT8^T) * 2^-22 -> bf16.
// NT, no split-K, 128x128 tile, BK=128 dbuf (64 KB LDS, 2 blocks/CU), 4
// waves each 64x64 = 2x2, two K=64 v_mfma_scale_f32_32x32x64_f8f6f4 groups
// per tile, ascending K. XCD supertile: 512 blocks; XCD j owns 8Mx8N rect.
__global__ __launch_bounds__(256) void k_gemm_fp8(const unsigned char* __restrict__ A,
                                                  const unsigned char* __restrict__ Bm,
                                                  unsigned short* __restrict__ C,
                                                  int N, int K) {
    __shared__ __align__(16) unsigned char As[2][128 * 128];  // 32 KB
    __shared__ __align__(16) unsigned char Bs[2][128 * 128];  // 32 KB
    const int tid  = threadIdx.x;
    const int wave = tid >> 6;
    const int lane = tid & 63;

    const int id = blockIdx.y * 32 + blockIdx.x;   // 0..511
    const int j8 = id & 7, s = id >> 3;            // s in [0,64)
    const int bm = ((j8 >> 2) * 8 + (s >> 3)) * 128;   // 16 M-blocks
    const int bn = ((j8 & 3) * 8 + (s & 7)) * 128;     // 32 N-blocks

    const int wr = (wave >> 1) * 64;
    const int wc = (wave & 1) * 64;
    const int l31 = lane & 31;
    const int half = lane >> 5;

    floatx16 acc[2][2] = {};

    // staging: lane covers row lr=lane>>3 (of each 8-row group), slot lane&7
    const int lr = lane >> 3;
    const int ks = ((lane & 7) ^ lr) * 16;  // bytes, pre-swizzled global chunk
    const unsigned char* ga = A  + (size_t)(bm + wave * 32 + lr) * K + ks;
    const unsigned char* gb = Bm + (size_t)(bn + wave * 32 + lr) * K + ks;

    auto stage = [&](int k0, int buf) {
        #pragma unroll
        for (int j = 0; j < 4; ++j) {
            async16(ga + (size_t)j * 8 * K + k0, &As[buf][wave * 4096 + j * 1024]);
            async16(gb + (size_t)j * 8 * K + k0, &Bs[buf][wave * 4096 + j * 1024]);
        }
    };

    const int nt = K >> 7;
    stage(0, 0);
    int cur = 0;
    for (int t = 0; t < nt; ++t) {
        __syncthreads();                       // drains own vmcnt -> tile t valid
        if (t + 1 < nt) stage((t + 1) << 7, cur ^ 1);

        const int sw = l31 & 7;
        #pragma unroll
        for (int m = 0; m < 2; ++m) {          // K=64 group, ascending
            const int c0 = ((4 * m + 2 * half) ^ sw) << 4;
            const int c1 = ((4 * m + 2 * half + 1) ^ sw) << 4;
            intx8 af[2], bf[2];
            #pragma unroll
            for (int tt = 0; tt < 2; ++tt) {
                const int ra = (wr + tt * 32 + l31) * 128;
                const int rb = (wc + tt * 32 + l31) * 128;
                intx4 a0 = *(const intx4*)&As[cur][ra + c0];
                intx4 a1 = *(const intx4*)&As[cur][ra + c1];
                intx4 b0 = *(const intx4*)&Bs[cur][rb + c0];
                intx4 b1 = *(const intx4*)&Bs[cur][rb + c1];
                af[tt] = (intx8){a0.x, a0.y, a0.z, a0.w, a1.x, a1.y, a1.z, a1.w};
                bf[tt] = (intx8){b0.x, b0.y, b0.z, b0.w, b1.x, b1.y, b1.z, b1.w};
            }
            #pragma unroll
            for (int mt = 0; mt < 2; ++mt)
                #pragma unroll
                for (int nt2 = 0; nt2 < 2; ++nt2)
                    acc[mt][nt2] = __builtin_amdgcn_mfma_scale_f32_32x32x64_f8f6f4(
                        af[mt], bf[nt2], acc[mt][nt2],
                        0, 0, 0, 0x7F7F7F7Fu, 0, 0x7F7F7F7Fu);
        }
        cur ^= 1;
    }

    const int row0 = 4 * half;
    #pragma unroll
    for (int mt = 0; mt < 2; ++mt) {
        #pragma unroll
        for (int nt2 = 0; nt2 < 2; ++nt2) {
            #pragma unroll
            for (int reg = 0; reg < 16; ++reg) {
                const int rr = bm + wr + mt * 32 + row0 + (reg & 3) + 8 * (reg >> 2);
                const int cc = bn + wc + nt2 * 32 + l31;
                C[(size_t)rr * N + cc] = f2bf(acc[mt][nt2][reg] * OUTSCALE1);
            }
        }
    }
}

// GEMM2 (i8, BK=128; fp16 partials, R11-validated): upd_z = fp16((ri8 *
// WnI8^T) * dq[col]). v_mfma_i32_32x32x32_i8, i32 accum exact; dequant then
// RTNE to fp16 in the epilogue. Split-K S2=2 in-grid -> 512 blocks (2/CU);
// XCD supertile 4Mx8N per XCD.
__global__ __launch_bounds__(256) void k_gemm_i8(const unsigned char* __restrict__ A,
                                                 const unsigned char* __restrict__ Bm,
                                                 const float* __restrict__ dq,
                                                 unsigned short* __restrict__ C,
                                                 int N, int K, int Ksub) {
    __shared__ __align__(16) unsigned char As[2][128 * 128];  // 32 KB
    __shared__ __align__(16) unsigned char Bs[2][128 * 128];  // 32 KB
    const int tid  = threadIdx.x;
    const int wave = tid >> 6;
    const int lane = tid & 63;

    const int id = blockIdx.y * 16 + blockIdx.x;   // 0..255 (z*256 = 0 mod 8)
    const int j8 = id & 7, s = id >> 3;            // s in [0,32)
    const int bm = ((j8 >> 1) * 4 + (s >> 3)) * 128;   // 16 M-blocks
    const int bn = ((j8 & 1) * 8 + (s & 7)) * 128;     // 16 N-blocks

    const int kz = blockIdx.z * Ksub;
    const int wr = (wave >> 1) * 64;
    const int wc = (wave & 1) * 64;
    const int l31 = lane & 31;
    const int half = lane >> 5;

    intx16 acc[2][2] = {};

    const int lr = lane >> 3;
    const int ks = ((lane & 7) ^ lr) * 16;  // bytes
    const unsigned char* ga = A  + (size_t)(bm + wave * 32 + lr) * K + ks;
    const unsigned char* gb = Bm + (size_t)(bn + wave * 32 + lr) * K + ks;

    auto stage = [&](int k0, int buf) {
        #pragma unroll
        for (int j = 0; j < 4; ++j) {
            async16(ga + (size_t)j * 8 * K + k0, &As[buf][wave * 4096 + j * 1024]);
            async16(gb + (size_t)j * 8 * K + k0, &Bs[buf][wave * 4096 + j * 1024]);
        }
    };

    const int nt = Ksub >> 7;
    stage(kz, 0);
    int cur = 0;
    for (int t = 0; t < nt; ++t) {
        __syncthreads();                       // drains own vmcnt -> tile t valid
        if (t + 1 < nt) stage(kz + ((t + 1) << 7), cur ^ 1);

        const int sw = l31 & 7;
        #pragma unroll
        for (int kk = 0; kk < 4; ++kk) {       // K=32 group, ascending
            const int slot = ((2 * kk + half) ^ sw) << 4;
            intx4 af[2], bf[2];
            #pragma unroll
            for (int tt = 0; tt < 2; ++tt) {
                af[tt] = *(const intx4*)&As[cur][(wr + tt * 32 + l31) * 128 + slot];
                bf[tt] = *(const intx4*)&Bs[cur][(wc + tt * 32 + l31) * 128 + slot];
            }
            #pragma unroll
            for (int mt = 0; mt < 2; ++mt)
                #pragma unroll
                for (int nt2 = 0; nt2 < 2; ++nt2)
                    acc[mt][nt2] = __builtin_amdgcn_mfma_i32_32x32x32_i8(
                        af[mt], bf[nt2], acc[mt][nt2], 0, 0, 0);
        }
        cur ^= 1;
    }

    unsigned short* Cz = C + (size_t)blockIdx.z * B_DIM * N;
    const int row0 = 4 * half;
    const float d0 = dq[bn + wc + l31];        // nt=0 column
    const float d1 = dq[bn + wc + 32 + l31];   // nt=1 column
    #pragma unroll
    for (int mt = 0; mt < 2; ++mt) {
        #pragma unroll
        for (int nt2 = 0; nt2 < 2; ++nt2) {
            const float d = nt2 ? d1 : d0;
            #pragma unroll
            for (int reg = 0; reg < 16; ++reg) {
                const int rr = bm + wr + mt * 32 + row0 + (reg & 3) + 8 * (reg >> 2);
                const int cc = bn + wc + nt2 * 32 + l31;
                Cz[(size_t)rr * N + cc] = f2h((float)acc[mt][nt2][reg] * d);
            }
        }
    }
}

// recon (bf16); s = rowsum(clip); ri8 = i8(min(xn*s*56/clip, 127))
__global__ __launch_bounds__(256) void k_make_ratio(const unsigned short* __restrict__ rec,
                                                    const unsigned int* __restrict__ xnb,
                                                    unsigned char* __restrict__ ri8) {
    const int row = blockIdx.x;
    float v[16];
    float s = 0.f;
    #pragma unroll
    for (int g = 0; g < 2; ++g) {
        const int idx = g * 256 + threadIdx.x;
        uint4 u = ((const uint4*)(rec + (size_t)row * FIN))[idx];
        float* p = v + g * 8;
        p[0] = bflo(u.x); p[1] = bfhi(u.x); p[2] = bflo(u.y); p[3] = bfhi(u.y);
        p[4] = bflo(u.z); p[5] = bfhi(u.z); p[6] = bflo(u.w); p[7] = bfhi(u.w);
        #pragma unroll
        for (int e = 0; e < 8; ++e) { p[e] = fmaxf(p[e], SMIN); s += p[e]; }
    }
    s = block_row_sum(s);
    const float ss = s * RS_I8;
    #pragma unroll
    for (int g = 0; g < 2; ++g) {
        const int idx = g * 256 + threadIdx.x;
        uint4 xu = ((const uint4*)(xnb + (size_t)row * (FIN / 2)))[idx];
        float* p = v + g * 8;
        float r[8];
        r[0] = bflo(xu.x) * ss / p[0]; r[1] = bfhi(xu.x) * ss / p[1];
        r[2] = bflo(xu.y) * ss / p[2]; r[3] = bfhi(xu.y) * ss / p[3];
        r[4] = bflo(xu.z) * ss / p[4]; r[5] = bfhi(xu.z) * ss / p[5];
        r[6] = bflo(xu.w) * ss / p[6]; r[7] = bfhi(xu.w) * ss / p[7];
        unsigned int q[8];
        #pragma unroll
        for (int e = 0; e < 8; ++e)
            q[e] = (unsigned int)(int)(fminf(r[e], 127.0f) + 0.5f);
        uint2 o;
        o.x = q[0] | (q[1] << 8) | (q[2] << 16) | (q[3] << 24);
        o.y = q[4] | (q[5] << 8) | (q[6] << 16) | (q[7] << 24);
        ((uint2*)(ri8 + (size_t)row * FIN))[idx] = o;
    }
}

// upd = sum fp16 partials; t = clip(h*upd); h' = t/rowsum(t).
// R12: h master fp16 (in [1e-5, ~2e-3], fp16-normal; storage rounding
// 2.4e-4 rel, 100x finer than the fp8 h8u already absorbed by the
// pipeline). h8u computed from pre-rounding fp32 values. Last iteration
// writes fp32 directly to out (outf != nullptr).
__global__ __launch_bounds__(256) void k_update_h(const unsigned short* __restrict__ hin,
                                                  const unsigned short* __restrict__ upd,
                                                  int nparts,
                                                  unsigned short* __restrict__ hout,
                                                  float* __restrict__ outf,
                                                  unsigned int* __restrict__ h8u) {
    const int row = blockIdx.x;
    float4 vals[2];
    float s = 0.f;
    #pragma unroll
    for (int i = 0; i < 2; ++i) {
        const int idx = i * 256 + threadIdx.x;
        uint2 hu = ((const uint2*)(hin + (size_t)row * FOUT))[idx];
        float4 hv;
        hv.x = h2f((unsigned short)(hu.x & 0xffffu));
        hv.y = h2f((unsigned short)(hu.x >> 16));
        hv.z = h2f((unsigned short)(hu.y & 0xffffu));
        hv.w = h2f((unsigned short)(hu.y >> 16));
        uint2 u = ((const uint2*)(upd + (size_t)row * FOUT))[idx];
        float4 uv;
        uv.x = h2f((unsigned short)(u.x & 0xffffu));
        uv.y = h2f((unsigned short)(u.x >> 16));
        uv.z = h2f((unsigned short)(u.y & 0xffffu));
        uv.w = h2f((unsigned short)(u.y >> 16));
        for (int z = 1; z < nparts; ++z) {
            uint2 q = ((const uint2*)(upd + (size_t)z * B_DIM * FOUT + (size_t)row * FOUT))[idx];
            uv.x += h2f((unsigned short)(q.x & 0xffffu));
            uv.y += h2f((unsigned short)(q.x >> 16));
            uv.z += h2f((unsigned short)(q.y & 0xffffu));
            uv.w += h2f((unsigned short)(q.y >> 16));
        }
        float4 v;
        v.x = fmaxf(hv.x * uv.x, SMIN);
        v.y = fmaxf(hv.y * uv.y, SMIN);
        v.z = fmaxf(hv.z * uv.z, SMIN);
        v.w = fmaxf(hv.w * uv.w, SMIN);
        vals[i] = v;
        s += (v.x + v.y) + (v.z + v.w);
    }
    s = block_row_sum(s);
    const float inv = 1.f / fmaxf(s, 1e-20f);
    unsigned int* bp = h8u + (size_t)row * (FOUT / 4);
    #pragma unroll
    for (int i = 0; i < 2; ++i) {
        const int idx = i * 256 + threadIdx.x;
        float4 v = vals[i];
        v.x *= inv; v.y *= inv; v.z *= inv; v.w *= inv;
        if (outf) {
            ((float4*)(outf + (size_t)row * FOUT))[idx] = v;
        } else {
            uint2 o;
            o.x = (unsigned int)f2h(v.x) | ((unsigned int)f2h(v.y) << 16);
            o.y = (unsigned int)f2h(v.z) | ((unsigned int)f2h(v.w) << 16);
            ((uint2*)(hout + (size_t)row * FOUT))[idx] = o;
        }
        unsigned int u = 0;
        u = (unsigned int)__builtin_amdgcn_cvt_pk_fp8_f32(v.x * HSCALE, v.y * HSCALE, (int)u, false);
        u = (unsigned int)__builtin_amdgcn_cvt_pk_fp8_f32(v.z * HSCALE, v.w * HSCALE, (int)u, true);
        bp[idx] = u;
    }
}

extern "C" void kernel_launch(void* const* d_in, const int* in_sizes, int n_in,
                              void* d_out, int out_size, void* d_ws, size_t ws_size,
                              hipStream_t stream) {
    const float* x = (const float*)d_in[0];
    const float* W = (const float*)d_in[1];
    float* out = (float*)d_out;

    const size_t UPD_PART = (size_t)B_DIM * FOUT * 2;  // fp16, 8.4 MB
    const size_t FIXED    = 81000000;                  // non-partial buffers
    int S2 = 1;
    if (ws_size >= FIXED + 2 * UPD_PART + (1 << 20)) {
        S2 = 2;
    }

    char* ws = (char*)d_ws;
    size_t off = 0;
    auto alloc = [&](size_t bytes) {
        void* p = ws + off;
        off += (bytes + 255) & ~(size_t)255;
        return p;
    };
    unsigned char*  WnT8 = (unsigned char*)alloc((size_t)FIN * FOUT);      // 8.4 MB
    unsigned char*  WnI8 = (unsigned char*)alloc((size_t)FOUT * FIN);      // 8.4 MB
    float*          dq   = (float*)alloc((size_t)FOUT * 4);                // 8 KB
    unsigned int*   h8u  = (unsigned int*)alloc((size_t)B_DIM * FOUT);     // 4.2 MB
    unsigned char*  ri8  = (unsigned char*)alloc((size_t)B_DIM * FIN);     // 8.4 MB
    unsigned int*   xnb  = (unsigned int*)alloc((size_t)B_DIM * FIN * 2);  // 16.8 MB
    unsigned short* h16  = (unsigned short*)alloc((size_t)B_DIM * FOUT * 2); // 8.4 MB
    unsigned short* rec  = (unsigned short*)alloc((size_t)B_DIM * FIN * 2);// 16.8 MB
    unsigned short* upd  = (unsigned short*)alloc(UPD_PART * S2);
    // Wn8 (fp8 master for the GEMM1 transpose) aliases rec: only live during
    // setup, before GEMM1 ever writes rec.
    unsigned char* Wn8 = (unsigned char*)rec;
    (void)in_sizes; (void)n_in; (void)out_size;

    k_norm_w<<<FOUT, 256, 0, stream>>>(W, Wn8, WnI8, dq);
    k_transpose_fp8<<<dim3(FIN / 32, FOUT / 32), dim3(32, 8), 0, stream>>>(Wn8, WnT8);
    k_norm_x<<<B_DIM, 256, 0, stream>>>(x, xnb);
    k_init_h<<<(B_DIM * FOUT) / (256 * 4), 256, 0, stream>>>((unsigned int*)h16, h8u);

    for (int it = 0; it < NITER; ++it) {
        // recon = h @ Wn : MX fp8 NT BK=128 dbuf, A=h8 (K=FOUT), B=WnT8, bf16 out
        k_gemm_fp8<<<dim3(FIN / 128, B_DIM / 128, 1), 256, 0, stream>>>(
            (const unsigned char*)h8u, WnT8, rec, FIN, FOUT);
        k_make_ratio<<<B_DIM, 256, 0, stream>>>(rec, xnb, ri8);
        // upd = r @ Wn^T : i8 NT BK=128 dbuf, split-K=2 in-grid, fp16 partials
        k_gemm_i8<<<dim3(FOUT / 128, B_DIM / 128, S2), 256, 0, stream>>>(
            ri8, WnI8, dq, upd, FOUT, FIN, FIN / S2);
        k_update_h<<<B_DIM, 256, 0, stream>>>(
            h16, upd, S2, h16, (it == NITER - 1) ? out : nullptr, h8u);
    }
}